// Round 1
// baseline (1365.396 us; speedup 1.0000x reference)
//
#include <hip/hip_runtime.h>

#define ND 128          // NODE_SIZE
#define ESZ 20          // EDGE_SIZE
#define NN 20000        // N_NODES
#define NE 600000       // N_EDGES
#define PI_F 3.14159265358979323846f
#define CUT 5.0f

__device__ __forceinline__ float silu_f(float x) { return x / (1.0f + __expf(-x)); }

// ---------------------------------------------------------------------------
// Kernel 0: initialize output accumulators: out_s = node_states_scalar,
//           out_v = node_states_vector  (atomics accumulate on top)
// ---------------------------------------------------------------------------
__global__ __launch_bounds__(256) void k_init(const float4* __restrict__ ns,
                                              const float4* __restrict__ nsv,
                                              float4* __restrict__ outs,
                                              float4* __restrict__ outv) {
    long i = (long)blockIdx.x * 256 + threadIdx.x;
    const long S4 = (long)NN * ND / 4;      // 640000
    const long V4 = (long)NN * 3 * ND / 4;  // 1920000
    if (i < S4) {
        outs[i] = ns[i];
    } else {
        long j = i - S4;
        if (j < V4) outv[j] = nsv[j];
    }
}

// ---------------------------------------------------------------------------
// Kernel 1: scalar_output = silu(ns @ Wm1 + bm1) @ Wm2 + bm2   -> ws (NN x 384)
// 8 nodes per 128-thread block; thread t owns output channels t, t+128, t+256
// ---------------------------------------------------------------------------
#define NPB_A 8
__global__ __launch_bounds__(128) void k_node_mlp(
    const float* __restrict__ ns,
    const float* __restrict__ Wm1, const float* __restrict__ bm1,
    const float* __restrict__ Wm2, const float* __restrict__ bm2,
    float* __restrict__ so) {
    __shared__ float ls_ns[NPB_A][ND];
    __shared__ float ls_h[NPB_A][ND];
    const int t = threadIdx.x;
    const int n0 = blockIdx.x * NPB_A;

    for (int nn = 0; nn < NPB_A; ++nn) {
        int node = n0 + nn;
        ls_ns[nn][t] = (node < NN) ? ns[(long)node * ND + t] : 0.0f;
    }
    __syncthreads();

    float hid[NPB_A];
    {
        float b = bm1[t];
        for (int nn = 0; nn < NPB_A; ++nn) hid[nn] = b;
    }
    for (int k = 0; k < ND; k += 4) {
        float w0 = Wm1[(k + 0) * ND + t];
        float w1 = Wm1[(k + 1) * ND + t];
        float w2 = Wm1[(k + 2) * ND + t];
        float w3 = Wm1[(k + 3) * ND + t];
        for (int nn = 0; nn < NPB_A; ++nn) {
            float4 x = *reinterpret_cast<const float4*>(&ls_ns[nn][k]);
            hid[nn] += x.x * w0 + x.y * w1 + x.z * w2 + x.w * w3;
        }
    }
    for (int nn = 0; nn < NPB_A; ++nn) ls_h[nn][t] = silu_f(hid[nn]);
    __syncthreads();

    float acc[NPB_A][3];
    for (int c = 0; c < 3; ++c) {
        float b = bm2[c * ND + t];
        for (int nn = 0; nn < NPB_A; ++nn) acc[nn][c] = b;
    }
    for (int k = 0; k < ND; k += 4) {
        float w[4][3];
        for (int q = 0; q < 4; ++q)
            for (int c = 0; c < 3; ++c)
                w[q][c] = Wm2[(k + q) * 384 + c * ND + t];
        for (int nn = 0; nn < NPB_A; ++nn) {
            float4 h = *reinterpret_cast<const float4*>(&ls_h[nn][k]);
            for (int c = 0; c < 3; ++c)
                acc[nn][c] += h.x * w[0][c] + h.y * w[1][c] + h.z * w[2][c] + h.w * w[3][c];
        }
    }
    for (int nn = 0; nn < NPB_A; ++nn) {
        int node = n0 + nn;
        if (node < NN)
            for (int c = 0; c < 3; ++c)
                so[(long)node * 384 + c * ND + t] = acc[nn][c];
    }
}

// ---------------------------------------------------------------------------
// Kernel 2: per-edge filter + messages, scatter-add into out_s / out_v.
// 256 threads = 2 edge slots x 128 channels. Wf columns live in registers.
// ---------------------------------------------------------------------------
#define EPB 64
__global__ __launch_bounds__(256) void k_edge(
    const float* __restrict__ es, const float* __restrict__ evec,
    const float* __restrict__ enorm, const int* __restrict__ eidx,
    const float* __restrict__ Wf, const float* __restrict__ bf,
    const float* __restrict__ so, const float* __restrict__ nsv,
    float* __restrict__ out_s, float* __restrict__ out_v) {
    const int t = threadIdx.x & 127;   // channel
    const int slot = threadIdx.x >> 7; // 0..1

    // Wf: (20, 384); column registers for channels t, t+128, t+256
    float wf[ESZ][3];
    for (int k = 0; k < ESZ; ++k)
        for (int c = 0; c < 3; ++c)
            wf[k][c] = Wf[k * 384 + c * ND + t];
    float bfr[3];
    for (int c = 0; c < 3; ++c) bfr[c] = bf[c * ND + t];

    const int e0 = blockIdx.x * EPB;
    for (int ei = slot; ei < EPB; ei += 2) {
        int e = e0 + ei;
        if (e >= NE) break;
        int src = eidx[2 * e];
        int dst = eidx[2 * e + 1];
        float nrm = enorm[e];
        float fc = (nrm < CUT) ? 0.5f * (__cosf(PI_F * nrm * (1.0f / CUT)) + 1.0f) : 0.0f;

        // edge_states row: 20 floats = 5 x float4 (80B, 16B aligned)
        const float4* es4 = reinterpret_cast<const float4*>(es + (long)e * ESZ);
        float esr[ESZ];
        for (int q = 0; q < 5; ++q) {
            float4 v = es4[q];
            esr[4 * q + 0] = v.x; esr[4 * q + 1] = v.y;
            esr[4 * q + 2] = v.z; esr[4 * q + 3] = v.w;
        }

        float fw[3] = {bfr[0], bfr[1], bfr[2]};
        for (int k = 0; k < ESZ; ++k)
            for (int c = 0; c < 3; ++c)
                fw[c] += esr[k] * wf[k][c];

        const float* sop = so + (long)src * 384;
        float fo0 = fw[0] * fc * sop[0 * ND + t];   // gate_nodes
        float fo1 = fw[1] * fc * sop[1 * ND + t];   // gate_edges
        float fo2 = fw[2] * fc * sop[2 * ND + t];   // messages_scalar

        atomicAdd(&out_s[(long)dst * ND + t], fo2);

        float ev0 = evec[3 * e + 0], ev1 = evec[3 * e + 1], ev2 = evec[3 * e + 2];
        const float* nvp = nsv + (long)src * 384;
        float m0 = nvp[0 * ND + t] * fo0 + fo1 * ev0;
        float m1 = nvp[1 * ND + t] * fo0 + fo1 * ev1;
        float m2 = nvp[2 * ND + t] * fo0 + fo1 * ev2;
        atomicAdd(&out_v[(long)dst * 384 + 0 * ND + t], m0);
        atomicAdd(&out_v[(long)dst * 384 + 1 * ND + t], m1);
        atomicAdd(&out_v[(long)dst * 384 + 2 * ND + t], m2);
    }
}

// ---------------------------------------------------------------------------
// Kernel 3: node update (in place on out_s / out_v)
//   Uv = v@WU, Vv = v@WV, a = silu([s, |Vv|^2] @ Wa1 + ba1) @ Wa2 + ba2
//   s += a_ss + a_sv * <Uv,Vv> ;  v += a_vv * Uv
// 4 nodes per 128-thread block; thread t owns channel t.
// ---------------------------------------------------------------------------
#define NPB_D 4
__global__ __launch_bounds__(128) void k_update(
    const float* __restrict__ WU, const float* __restrict__ WV,
    const float* __restrict__ Wa1, const float* __restrict__ ba1,
    const float* __restrict__ Wa2, const float* __restrict__ ba2,
    float* __restrict__ out_s, float* __restrict__ out_v) {
    __shared__ float ls_s[NPB_D][ND];
    __shared__ float ls_v[NPB_D][3 * ND];
    __shared__ float ls_q[NPB_D][ND];
    __shared__ float ls_h[NPB_D][ND];
    const int t = threadIdx.x;
    const int n0 = blockIdx.x * NPB_D;

    for (int nn = 0; nn < NPB_D; ++nn) {
        int node = n0 + nn;
        if (node < NN) {
            ls_s[nn][t] = out_s[(long)node * ND + t];
            for (int ax = 0; ax < 3; ++ax)
                ls_v[nn][ax * ND + t] = out_v[(long)node * 384 + ax * ND + t];
        } else {
            ls_s[nn][t] = 0.0f;
            for (int ax = 0; ax < 3; ++ax) ls_v[nn][ax * ND + t] = 0.0f;
        }
    }
    __syncthreads();

    float Uv[NPB_D][3] = {}, Vv[NPB_D][3] = {};
    for (int d = 0; d < ND; d += 4) {
        float wu[4], wv[4];
        for (int q = 0; q < 4; ++q) {
            wu[q] = WU[(d + q) * ND + t];
            wv[q] = WV[(d + q) * ND + t];
        }
        for (int nn = 0; nn < NPB_D; ++nn)
            for (int ax = 0; ax < 3; ++ax) {
                float4 vx = *reinterpret_cast<const float4*>(&ls_v[nn][ax * ND + d]);
                Uv[nn][ax] += vx.x * wu[0] + vx.y * wu[1] + vx.z * wu[2] + vx.w * wu[3];
                Vv[nn][ax] += vx.x * wv[0] + vx.y * wv[1] + vx.z * wv[2] + vx.w * wv[3];
            }
    }
    for (int nn = 0; nn < NPB_D; ++nn)
        ls_q[nn][t] = Vv[nn][0] * Vv[nn][0] + Vv[nn][1] * Vv[nn][1] + Vv[nn][2] * Vv[nn][2];
    __syncthreads();

    float hid[NPB_D];
    {
        float b = ba1[t];
        for (int nn = 0; nn < NPB_D; ++nn) hid[nn] = b;
    }
    for (int k = 0; k < ND; k += 4) {
        float w[4];
        for (int q = 0; q < 4; ++q) w[q] = Wa1[(k + q) * ND + t];
        for (int nn = 0; nn < NPB_D; ++nn) {
            float4 x = *reinterpret_cast<const float4*>(&ls_s[nn][k]);
            hid[nn] += x.x * w[0] + x.y * w[1] + x.z * w[2] + x.w * w[3];
        }
    }
    for (int k = 0; k < ND; k += 4) {
        float w[4];
        for (int q = 0; q < 4; ++q) w[q] = Wa1[(ND + k + q) * ND + t];
        for (int nn = 0; nn < NPB_D; ++nn) {
            float4 x = *reinterpret_cast<const float4*>(&ls_q[nn][k]);
            hid[nn] += x.x * w[0] + x.y * w[1] + x.z * w[2] + x.w * w[3];
        }
    }
    for (int nn = 0; nn < NPB_D; ++nn) ls_h[nn][t] = silu_f(hid[nn]);
    __syncthreads();

    float a[NPB_D][3];
    for (int c = 0; c < 3; ++c) {
        float b = ba2[c * ND + t];
        for (int nn = 0; nn < NPB_D; ++nn) a[nn][c] = b;
    }
    for (int k = 0; k < ND; k += 4) {
        float w[4][3];
        for (int q = 0; q < 4; ++q)
            for (int c = 0; c < 3; ++c)
                w[q][c] = Wa2[(k + q) * 384 + c * ND + t];
        for (int nn = 0; nn < NPB_D; ++nn) {
            float4 h = *reinterpret_cast<const float4*>(&ls_h[nn][k]);
            for (int c = 0; c < 3; ++c)
                a[nn][c] += h.x * w[0][c] + h.y * w[1][c] + h.z * w[2][c] + h.w * w[3][c];
        }
    }

    for (int nn = 0; nn < NPB_D; ++nn) {
        int node = n0 + nn;
        if (node >= NN) continue;
        float ip = Uv[nn][0] * Vv[nn][0] + Uv[nn][1] * Vv[nn][1] + Uv[nn][2] * Vv[nn][2];
        out_s[(long)node * ND + t] = ls_s[nn][t] + a[nn][0] + a[nn][1] * ip;
        for (int ax = 0; ax < 3; ++ax)
            out_v[(long)node * 384 + ax * ND + t] =
                ls_v[nn][ax * ND + t] + a[nn][2] * Uv[nn][ax];
    }
}

// ---------------------------------------------------------------------------
extern "C" void kernel_launch(void* const* d_in, const int* in_sizes, int n_in,
                              void* d_out, int out_size, void* d_ws, size_t ws_size,
                              hipStream_t stream) {
    const float* ns    = (const float*)d_in[0];
    const float* nsv   = (const float*)d_in[1];
    const float* es    = (const float*)d_in[2];
    const float* evec  = (const float*)d_in[3];
    const float* enorm = (const float*)d_in[4];
    const int*   eidx  = (const int*)d_in[5];
    const float* Wf    = (const float*)d_in[6];
    const float* bf    = (const float*)d_in[7];
    const float* Wm1   = (const float*)d_in[8];
    const float* bm1   = (const float*)d_in[9];
    const float* Wm2   = (const float*)d_in[10];
    const float* bm2   = (const float*)d_in[11];
    const float* WU    = (const float*)d_in[12];
    const float* WV    = (const float*)d_in[13];
    const float* Wa1   = (const float*)d_in[14];
    const float* ba1   = (const float*)d_in[15];
    const float* Wa2   = (const float*)d_in[16];
    const float* ba2   = (const float*)d_in[17];

    float* out_s = (float*)d_out;
    float* out_v = out_s + (size_t)NN * ND;
    float* so    = (float*)d_ws;  // NN x 384 scalar_output

    k_init<<<10000, 256, 0, stream>>>((const float4*)ns, (const float4*)nsv,
                                      (float4*)out_s, (float4*)out_v);
    k_node_mlp<<<(NN + NPB_A - 1) / NPB_A, 128, 0, stream>>>(ns, Wm1, bm1, Wm2, bm2, so);
    k_edge<<<(NE + EPB - 1) / EPB, 256, 0, stream>>>(es, evec, enorm, eidx, Wf, bf,
                                                     so, nsv, out_s, out_v);
    k_update<<<(NN + NPB_D - 1) / NPB_D, 128, 0, stream>>>(WU, WV, Wa1, ba1, Wa2, ba2,
                                                           out_s, out_v);
}

// Round 2
// 1012.105 us; speedup vs baseline: 1.3491x; 1.3491x over previous
//
#include <hip/hip_runtime.h>

#define ND 128          // NODE_SIZE
#define ESZ 20          // EDGE_SIZE
#define NN 20000        // N_NODES
#define NE 600000       // N_EDGES
#define PI_F 3.14159265358979323846f
#define CUT 5.0f

__device__ __forceinline__ float silu_f(float x) { return x / (1.0f + __expf(-x)); }

// ---------------------------------------------------------------------------
// Kernel 1: scalar_output = silu(ns @ Wm1 + bm1) @ Wm2 + bm2   -> ws (NN x 384)
// ---------------------------------------------------------------------------
#define NPB_A 8
__global__ __launch_bounds__(128) void k_node_mlp(
    const float* __restrict__ ns,
    const float* __restrict__ Wm1, const float* __restrict__ bm1,
    const float* __restrict__ Wm2, const float* __restrict__ bm2,
    float* __restrict__ so) {
    __shared__ float ls_ns[NPB_A][ND];
    __shared__ float ls_h[NPB_A][ND];
    const int t = threadIdx.x;
    const int n0 = blockIdx.x * NPB_A;

    for (int nn = 0; nn < NPB_A; ++nn) {
        int node = n0 + nn;
        ls_ns[nn][t] = (node < NN) ? ns[(long)node * ND + t] : 0.0f;
    }
    __syncthreads();

    float hid[NPB_A];
    {
        float b = bm1[t];
        for (int nn = 0; nn < NPB_A; ++nn) hid[nn] = b;
    }
    for (int k = 0; k < ND; k += 4) {
        float w0 = Wm1[(k + 0) * ND + t];
        float w1 = Wm1[(k + 1) * ND + t];
        float w2 = Wm1[(k + 2) * ND + t];
        float w3 = Wm1[(k + 3) * ND + t];
        for (int nn = 0; nn < NPB_A; ++nn) {
            float4 x = *reinterpret_cast<const float4*>(&ls_ns[nn][k]);
            hid[nn] += x.x * w0 + x.y * w1 + x.z * w2 + x.w * w3;
        }
    }
    for (int nn = 0; nn < NPB_A; ++nn) ls_h[nn][t] = silu_f(hid[nn]);
    __syncthreads();

    float acc[NPB_A][3];
    for (int c = 0; c < 3; ++c) {
        float b = bm2[c * ND + t];
        for (int nn = 0; nn < NPB_A; ++nn) acc[nn][c] = b;
    }
    for (int k = 0; k < ND; k += 4) {
        float w[4][3];
        for (int q = 0; q < 4; ++q)
            for (int c = 0; c < 3; ++c)
                w[q][c] = Wm2[(k + q) * 384 + c * ND + t];
        for (int nn = 0; nn < NPB_A; ++nn) {
            float4 h = *reinterpret_cast<const float4*>(&ls_h[nn][k]);
            for (int c = 0; c < 3; ++c)
                acc[nn][c] += h.x * w[0][c] + h.y * w[1][c] + h.z * w[2][c] + h.w * w[3][c];
        }
    }
    for (int nn = 0; nn < NPB_A; ++nn) {
        int node = n0 + nn;
        if (node < NN)
            for (int c = 0; c < 3; ++c)
                so[(long)node * 384 + c * ND + t] = acc[nn][c];
    }
}

// ---------------------------------------------------------------------------
// CSR build: histogram by dst, prefix scan, scatter permutation
// ---------------------------------------------------------------------------
__global__ __launch_bounds__(256) void k_hist(const int* __restrict__ eidx,
                                              int* __restrict__ counts) {
    int e = blockIdx.x * 256 + threadIdx.x;
    if (e < NE) atomicAdd(&counts[eidx[2 * e + 1]], 1);
}

#define SCAN_T 1024
__global__ __launch_bounds__(SCAN_T) void k_scan(const int* __restrict__ counts,
                                                 int* __restrict__ offsets,
                                                 int* __restrict__ cursor) {
    __shared__ int part[SCAN_T];
    const int t = threadIdx.x;
    const int CPT = (NN + SCAN_T - 1) / SCAN_T;  // 20
    const int base = t * CPT;
    int sum = 0;
    for (int i = 0; i < CPT; ++i) {
        int idx = base + i;
        if (idx < NN) sum += counts[idx];
    }
    part[t] = sum;
    __syncthreads();
    for (int off = 1; off < SCAN_T; off <<= 1) {
        int v = (t >= off) ? part[t - off] : 0;
        __syncthreads();
        part[t] += v;
        __syncthreads();
    }
    int run = (t == 0) ? 0 : part[t - 1];
    for (int i = 0; i < CPT; ++i) {
        int idx = base + i;
        if (idx < NN) {
            offsets[idx] = run;
            cursor[idx] = run;
            run += counts[idx];
        }
    }
    if (t == SCAN_T - 1) offsets[NN] = run;
}

__global__ __launch_bounds__(256) void k_scatter(const int* __restrict__ eidx,
                                                 int* __restrict__ cursor,
                                                 int* __restrict__ perm) {
    int e = blockIdx.x * 256 + threadIdx.x;
    if (e < NE) {
        int pos = atomicAdd(&cursor[eidx[2 * e + 1]], 1);
        perm[pos] = e;
    }
}

// ---------------------------------------------------------------------------
// Kernel 2: per-node gather. One block per dst node; 2 edge slots x 128 ch.
// Recomputes the Wf filter in registers; accumulates s/v in registers;
// single write per output row (fused with ns/nsv base add). No atomics.
// ---------------------------------------------------------------------------
#define GS 2
__global__ __launch_bounds__(256) void k_gather(
    const float* __restrict__ es, const float* __restrict__ evec,
    const float* __restrict__ enorm, const int* __restrict__ eidx,
    const int* __restrict__ offsets, const int* __restrict__ perm,
    const float* __restrict__ Wf, const float* __restrict__ bf,
    const float* __restrict__ so, const float* __restrict__ ns,
    const float* __restrict__ nsv,
    float* __restrict__ out_s, float* __restrict__ out_v) {
    const int t = threadIdx.x & 127;   // channel
    const int slot = threadIdx.x >> 7; // 0..1
    const int node = blockIdx.x;

    float wf[ESZ][3];
    for (int k = 0; k < ESZ; ++k)
        for (int c = 0; c < 3; ++c)
            wf[k][c] = Wf[k * 384 + c * ND + t];
    float bfr[3];
    for (int c = 0; c < 3; ++c) bfr[c] = bf[c * ND + t];

    const int beg = offsets[node];
    const int end = offsets[node + 1];

    float acc_s = 0.0f, acc_v0 = 0.0f, acc_v1 = 0.0f, acc_v2 = 0.0f;

    for (int i = beg + slot; i < end; i += GS) {
        int e = perm[i];
        int src = eidx[2 * e];
        float nrm = enorm[e];
        float fc = (nrm < CUT) ? 0.5f * (__cosf(PI_F * nrm * (1.0f / CUT)) + 1.0f) : 0.0f;

        const float4* es4 = reinterpret_cast<const float4*>(es + (long)e * ESZ);
        float esr[ESZ];
        for (int q = 0; q < 5; ++q) {
            float4 v = es4[q];
            esr[4 * q + 0] = v.x; esr[4 * q + 1] = v.y;
            esr[4 * q + 2] = v.z; esr[4 * q + 3] = v.w;
        }

        float fw0 = bfr[0], fw1 = bfr[1], fw2 = bfr[2];
        for (int k = 0; k < ESZ; ++k) {
            fw0 += esr[k] * wf[k][0];
            fw1 += esr[k] * wf[k][1];
            fw2 += esr[k] * wf[k][2];
        }

        const float* sop = so + (long)src * 384;
        float fo0 = fw0 * fc * sop[0 * ND + t];   // gate_nodes
        float fo1 = fw1 * fc * sop[1 * ND + t];   // gate_edges
        float fo2 = fw2 * fc * sop[2 * ND + t];   // messages_scalar

        acc_s += fo2;

        float ev0 = evec[3 * e + 0], ev1 = evec[3 * e + 1], ev2 = evec[3 * e + 2];
        const float* nvp = nsv + (long)src * 384;
        acc_v0 += nvp[0 * ND + t] * fo0 + fo1 * ev0;
        acc_v1 += nvp[1 * ND + t] * fo0 + fo1 * ev1;
        acc_v2 += nvp[2 * ND + t] * fo0 + fo1 * ev2;
    }

    __shared__ float red[4][128];
    if (slot == 1) {
        red[0][t] = acc_s; red[1][t] = acc_v0; red[2][t] = acc_v1; red[3][t] = acc_v2;
    }
    __syncthreads();
    if (slot == 0) {
        acc_s  += red[0][t];
        acc_v0 += red[1][t];
        acc_v1 += red[2][t];
        acc_v2 += red[3][t];
        out_s[(long)node * ND + t] = ns[(long)node * ND + t] + acc_s;
        out_v[(long)node * 384 + 0 * ND + t] = nsv[(long)node * 384 + 0 * ND + t] + acc_v0;
        out_v[(long)node * 384 + 1 * ND + t] = nsv[(long)node * 384 + 1 * ND + t] + acc_v1;
        out_v[(long)node * 384 + 2 * ND + t] = nsv[(long)node * 384 + 2 * ND + t] + acc_v2;
    }
}

// ---------------------------------------------------------------------------
// Kernel 3: node update (in place on out_s / out_v) — unchanged
// ---------------------------------------------------------------------------
#define NPB_D 4
__global__ __launch_bounds__(128) void k_update(
    const float* __restrict__ WU, const float* __restrict__ WV,
    const float* __restrict__ Wa1, const float* __restrict__ ba1,
    const float* __restrict__ Wa2, const float* __restrict__ ba2,
    float* __restrict__ out_s, float* __restrict__ out_v) {
    __shared__ float ls_s[NPB_D][ND];
    __shared__ float ls_v[NPB_D][3 * ND];
    __shared__ float ls_q[NPB_D][ND];
    __shared__ float ls_h[NPB_D][ND];
    const int t = threadIdx.x;
    const int n0 = blockIdx.x * NPB_D;

    for (int nn = 0; nn < NPB_D; ++nn) {
        int node = n0 + nn;
        if (node < NN) {
            ls_s[nn][t] = out_s[(long)node * ND + t];
            for (int ax = 0; ax < 3; ++ax)
                ls_v[nn][ax * ND + t] = out_v[(long)node * 384 + ax * ND + t];
        } else {
            ls_s[nn][t] = 0.0f;
            for (int ax = 0; ax < 3; ++ax) ls_v[nn][ax * ND + t] = 0.0f;
        }
    }
    __syncthreads();

    float Uv[NPB_D][3] = {}, Vv[NPB_D][3] = {};
    for (int d = 0; d < ND; d += 4) {
        float wu[4], wv[4];
        for (int q = 0; q < 4; ++q) {
            wu[q] = WU[(d + q) * ND + t];
            wv[q] = WV[(d + q) * ND + t];
        }
        for (int nn = 0; nn < NPB_D; ++nn)
            for (int ax = 0; ax < 3; ++ax) {
                float4 vx = *reinterpret_cast<const float4*>(&ls_v[nn][ax * ND + d]);
                Uv[nn][ax] += vx.x * wu[0] + vx.y * wu[1] + vx.z * wu[2] + vx.w * wu[3];
                Vv[nn][ax] += vx.x * wv[0] + vx.y * wv[1] + vx.z * wv[2] + vx.w * wv[3];
            }
    }
    for (int nn = 0; nn < NPB_D; ++nn)
        ls_q[nn][t] = Vv[nn][0] * Vv[nn][0] + Vv[nn][1] * Vv[nn][1] + Vv[nn][2] * Vv[nn][2];
    __syncthreads();

    float hid[NPB_D];
    {
        float b = ba1[t];
        for (int nn = 0; nn < NPB_D; ++nn) hid[nn] = b;
    }
    for (int k = 0; k < ND; k += 4) {
        float w[4];
        for (int q = 0; q < 4; ++q) w[q] = Wa1[(k + q) * ND + t];
        for (int nn = 0; nn < NPB_D; ++nn) {
            float4 x = *reinterpret_cast<const float4*>(&ls_s[nn][k]);
            hid[nn] += x.x * w[0] + x.y * w[1] + x.z * w[2] + x.w * w[3];
        }
    }
    for (int k = 0; k < ND; k += 4) {
        float w[4];
        for (int q = 0; q < 4; ++q) w[q] = Wa1[(ND + k + q) * ND + t];
        for (int nn = 0; nn < NPB_D; ++nn) {
            float4 x = *reinterpret_cast<const float4*>(&ls_q[nn][k]);
            hid[nn] += x.x * w[0] + x.y * w[1] + x.z * w[2] + x.w * w[3];
        }
    }
    for (int nn = 0; nn < NPB_D; ++nn) ls_h[nn][t] = silu_f(hid[nn]);
    __syncthreads();

    float a[NPB_D][3];
    for (int c = 0; c < 3; ++c) {
        float b = ba2[c * ND + t];
        for (int nn = 0; nn < NPB_D; ++nn) a[nn][c] = b;
    }
    for (int k = 0; k < ND; k += 4) {
        float w[4][3];
        for (int q = 0; q < 4; ++q)
            for (int c = 0; c < 3; ++c)
                w[q][c] = Wa2[(k + q) * 384 + c * ND + t];
        for (int nn = 0; nn < NPB_D; ++nn) {
            float4 h = *reinterpret_cast<const float4*>(&ls_h[nn][k]);
            for (int c = 0; c < 3; ++c)
                a[nn][c] += h.x * w[0][c] + h.y * w[1][c] + h.z * w[2][c] + h.w * w[3][c];
        }
    }

    for (int nn = 0; nn < NPB_D; ++nn) {
        int node = n0 + nn;
        if (node >= NN) continue;
        float ip = Uv[nn][0] * Vv[nn][0] + Uv[nn][1] * Vv[nn][1] + Uv[nn][2] * Vv[nn][2];
        out_s[(long)node * ND + t] = ls_s[nn][t] + a[nn][0] + a[nn][1] * ip;
        for (int ax = 0; ax < 3; ++ax)
            out_v[(long)node * 384 + ax * ND + t] =
                ls_v[nn][ax * ND + t] + a[nn][2] * Uv[nn][ax];
    }
}

// ---------------------------------------------------------------------------
extern "C" void kernel_launch(void* const* d_in, const int* in_sizes, int n_in,
                              void* d_out, int out_size, void* d_ws, size_t ws_size,
                              hipStream_t stream) {
    const float* ns    = (const float*)d_in[0];
    const float* nsv   = (const float*)d_in[1];
    const float* es    = (const float*)d_in[2];
    const float* evec  = (const float*)d_in[3];
    const float* enorm = (const float*)d_in[4];
    const int*   eidx  = (const int*)d_in[5];
    const float* Wf    = (const float*)d_in[6];
    const float* bf    = (const float*)d_in[7];
    const float* Wm1   = (const float*)d_in[8];
    const float* bm1   = (const float*)d_in[9];
    const float* Wm2   = (const float*)d_in[10];
    const float* bm2   = (const float*)d_in[11];
    const float* WU    = (const float*)d_in[12];
    const float* WV    = (const float*)d_in[13];
    const float* Wa1   = (const float*)d_in[14];
    const float* ba1   = (const float*)d_in[15];
    const float* Wa2   = (const float*)d_in[16];
    const float* ba2   = (const float*)d_in[17];

    float* out_s = (float*)d_out;
    float* out_v = out_s + (size_t)NN * ND;

    // workspace layout
    char* w = (char*)d_ws;
    float* so     = (float*)w;                 w += (size_t)NN * 384 * sizeof(float);
    int*   counts = (int*)w;                   w += (size_t)NN * sizeof(int);
    int*   offs   = (int*)w;                   w += (size_t)(NN + 1) * sizeof(int);
    int*   cursor = (int*)w;                   w += (size_t)NN * sizeof(int);
    int*   perm   = (int*)w;                   w += (size_t)NE * sizeof(int);

    hipMemsetAsync(counts, 0, (size_t)NN * sizeof(int), stream);
    k_hist<<<(NE + 255) / 256, 256, 0, stream>>>(eidx, counts);
    k_scan<<<1, SCAN_T, 0, stream>>>(counts, offs, cursor);
    k_scatter<<<(NE + 255) / 256, 256, 0, stream>>>(eidx, cursor, perm);
    k_node_mlp<<<(NN + NPB_A - 1) / NPB_A, 128, 0, stream>>>(ns, Wm1, bm1, Wm2, bm2, so);
    k_gather<<<NN, 256, 0, stream>>>(es, evec, enorm, eidx, offs, perm, Wf, bf,
                                     so, ns, nsv, out_s, out_v);
    k_update<<<(NN + NPB_D - 1) / NPB_D, 128, 0, stream>>>(WU, WV, Wa1, ba1, Wa2, ba2,
                                                           out_s, out_v);
}

// Round 3
// 978.391 us; speedup vs baseline: 1.3956x; 1.0345x over previous
//
#include <hip/hip_runtime.h>

#define ND 128          // NODE_SIZE
#define ESZ 20          // EDGE_SIZE
#define NN 20000        // N_NODES
#define NE 600000       // N_EDGES
#define PI_F 3.14159265358979323846f
#define CUT 5.0f

__device__ __forceinline__ float silu_f(float x) { return x / (1.0f + __expf(-x)); }

// ---------------------------------------------------------------------------
// Kernel 0: out_s = ns, out_v = nsv (edge kernel atomically adds on top)
// ---------------------------------------------------------------------------
__global__ __launch_bounds__(256) void k_init(const float4* __restrict__ ns,
                                              const float4* __restrict__ nsv,
                                              float4* __restrict__ outs,
                                              float4* __restrict__ outv) {
    long i = (long)blockIdx.x * 256 + threadIdx.x;
    const long S4 = (long)NN * ND / 4;
    const long V4 = (long)NN * 3 * ND / 4;
    if (i < S4) {
        outs[i] = ns[i];
    } else {
        long j = i - S4;
        if (j < V4) outv[j] = nsv[j];
    }
}

// ---------------------------------------------------------------------------
// Kernel 1: scalar_output = silu(ns @ Wm1 + bm1) @ Wm2 + bm2   -> ws (NN x 384)
// ---------------------------------------------------------------------------
#define NPB_A 16
__global__ __launch_bounds__(128) void k_node_mlp(
    const float* __restrict__ ns,
    const float* __restrict__ Wm1, const float* __restrict__ bm1,
    const float* __restrict__ Wm2, const float* __restrict__ bm2,
    float* __restrict__ so) {
    __shared__ float ls_ns[NPB_A][ND];
    __shared__ float ls_h[NPB_A][ND];
    const int t = threadIdx.x;
    const int n0 = blockIdx.x * NPB_A;

    for (int nn = 0; nn < NPB_A; ++nn) {
        int node = n0 + nn;
        ls_ns[nn][t] = (node < NN) ? ns[(long)node * ND + t] : 0.0f;
    }
    __syncthreads();

    float hid[NPB_A];
    {
        float b = bm1[t];
        for (int nn = 0; nn < NPB_A; ++nn) hid[nn] = b;
    }
    for (int k = 0; k < ND; k += 4) {
        float w0 = Wm1[(k + 0) * ND + t];
        float w1 = Wm1[(k + 1) * ND + t];
        float w2 = Wm1[(k + 2) * ND + t];
        float w3 = Wm1[(k + 3) * ND + t];
        for (int nn = 0; nn < NPB_A; ++nn) {
            float4 x = *reinterpret_cast<const float4*>(&ls_ns[nn][k]);
            hid[nn] += x.x * w0 + x.y * w1 + x.z * w2 + x.w * w3;
        }
    }
    for (int nn = 0; nn < NPB_A; ++nn) ls_h[nn][t] = silu_f(hid[nn]);
    __syncthreads();

    float acc[NPB_A][3];
    for (int c = 0; c < 3; ++c) {
        float b = bm2[c * ND + t];
        for (int nn = 0; nn < NPB_A; ++nn) acc[nn][c] = b;
    }
    for (int k = 0; k < ND; k += 4) {
        float w[4][3];
        for (int q = 0; q < 4; ++q)
            for (int c = 0; c < 3; ++c)
                w[q][c] = Wm2[(k + q) * 384 + c * ND + t];
        for (int nn = 0; nn < NPB_A; ++nn) {
            float4 h = *reinterpret_cast<const float4*>(&ls_h[nn][k]);
            for (int c = 0; c < 3; ++c)
                acc[nn][c] += h.x * w[0][c] + h.y * w[1][c] + h.z * w[2][c] + h.w * w[3][c];
        }
    }
    for (int nn = 0; nn < NPB_A; ++nn) {
        int node = n0 + nn;
        if (node < NN)
            for (int c = 0; c < 3; ++c)
                so[(long)node * 384 + c * ND + t] = acc[nn][c];
    }
}

// ---------------------------------------------------------------------------
// CSR build: histogram by dst, prefix scan, scatter permutation
// ---------------------------------------------------------------------------
__global__ __launch_bounds__(256) void k_hist(const int* __restrict__ eidx,
                                              int* __restrict__ counts) {
    int e = blockIdx.x * 256 + threadIdx.x;
    if (e < NE) atomicAdd(&counts[eidx[2 * e + 1]], 1);
}

#define SCAN_T 1024
__global__ __launch_bounds__(SCAN_T) void k_scan(const int* __restrict__ counts,
                                                 int* __restrict__ offsets,
                                                 int* __restrict__ cursor) {
    __shared__ int part[SCAN_T];
    const int t = threadIdx.x;
    const int CPT = (NN + SCAN_T - 1) / SCAN_T;
    const int base = t * CPT;
    int sum = 0;
    for (int i = 0; i < CPT; ++i) {
        int idx = base + i;
        if (idx < NN) sum += counts[idx];
    }
    part[t] = sum;
    __syncthreads();
    for (int off = 1; off < SCAN_T; off <<= 1) {
        int v = (t >= off) ? part[t - off] : 0;
        __syncthreads();
        part[t] += v;
        __syncthreads();
    }
    int run = (t == 0) ? 0 : part[t - 1];
    for (int i = 0; i < CPT; ++i) {
        int idx = base + i;
        if (idx < NN) {
            offsets[idx] = run;
            cursor[idx] = run;
            run += counts[idx];
        }
    }
    if (t == SCAN_T - 1) offsets[NN] = run;
}

__global__ __launch_bounds__(256) void k_scatter(const int* __restrict__ eidx,
                                                 int* __restrict__ cursor,
                                                 int* __restrict__ perm) {
    int e = blockIdx.x * 256 + threadIdx.x;
    if (e < NE) {
        int pos = atomicAdd(&cursor[eidx[2 * e + 1]], 1);
        perm[pos] = e;
    }
}

// ---------------------------------------------------------------------------
// Kernel 2: edge-parallel segmented reduction over dst-sorted edges.
// 8192 groups x 128 threads; each group owns a contiguous run of sorted
// edges, accumulates per-channel (s,v0,v1,v2) in registers while dst is
// unchanged, flushes via atomicAdd on segment change. 3-stage software
// pipeline: [i+2] e-indexed loads, [i+1] src gathers, [i] compute.
// ---------------------------------------------------------------------------
#define NGRP 8192
#define RUN ((NE + NGRP - 1) / NGRP)   // 74

struct EData {
    int src, dst;
    float nrm, ev0, ev1, ev2;
    float er[ESZ];
};
struct GData { float so0, so1, so2, nv0, nv1, nv2; };

__device__ __forceinline__ EData load_e(int e, const int2* __restrict__ eidx2,
                                        const float* __restrict__ enorm,
                                        const float* __restrict__ evec,
                                        const float* __restrict__ es) {
    EData d;
    int2 sd = eidx2[e];
    d.src = sd.x; d.dst = sd.y;
    d.nrm = enorm[e];
    d.ev0 = evec[3 * e + 0]; d.ev1 = evec[3 * e + 1]; d.ev2 = evec[3 * e + 2];
    const float4* p = reinterpret_cast<const float4*>(es + (long)e * ESZ);
    float4 a = p[0], b = p[1], c = p[2], x = p[3], y = p[4];
    d.er[0]=a.x; d.er[1]=a.y; d.er[2]=a.z; d.er[3]=a.w;
    d.er[4]=b.x; d.er[5]=b.y; d.er[6]=b.z; d.er[7]=b.w;
    d.er[8]=c.x; d.er[9]=c.y; d.er[10]=c.z; d.er[11]=c.w;
    d.er[12]=x.x; d.er[13]=x.y; d.er[14]=x.z; d.er[15]=x.w;
    d.er[16]=y.x; d.er[17]=y.y; d.er[18]=y.z; d.er[19]=y.w;
    return d;
}

__device__ __forceinline__ GData load_g(int src, int t,
                                        const float* __restrict__ so,
                                        const float* __restrict__ nsv) {
    GData g;
    const float* sp = so + (long)src * 384;
    g.so0 = sp[t]; g.so1 = sp[ND + t]; g.so2 = sp[2 * ND + t];
    const float* np = nsv + (long)src * 384;
    g.nv0 = np[t]; g.nv1 = np[ND + t]; g.nv2 = np[2 * ND + t];
    return g;
}

__global__ __launch_bounds__(256) void k_edge2(
    const float* __restrict__ es, const float* __restrict__ evec,
    const float* __restrict__ enorm, const int2* __restrict__ eidx2,
    const int* __restrict__ perm,
    const float* __restrict__ Wf, const float* __restrict__ bf,
    const float* __restrict__ so, const float* __restrict__ nsv,
    float* __restrict__ out_s, float* __restrict__ out_v) {
    const int t = threadIdx.x & 127;
    const int grp = blockIdx.x * 2 + (threadIdx.x >> 7);
    const int beg = grp * RUN;
    const int end = (beg + RUN < NE) ? beg + RUN : NE;
    if (beg >= end) return;

    // Wf columns for channels t, t+128, t+256 in registers
    float wf[ESZ][3];
#pragma unroll
    for (int k = 0; k < ESZ; ++k)
        for (int c = 0; c < 3; ++c)
            wf[k][c] = Wf[k * 384 + c * ND + t];
    float bfr[3];
    for (int c = 0; c < 3; ++c) bfr[c] = bf[c * ND + t];

    // pipeline prologue
    int e_a = perm[beg];
    int i1 = (beg + 1 < end) ? beg + 1 : end - 1;
    int e_b = perm[i1];
    EData A = load_e(e_a, eidx2, enorm, evec, es);
    GData GA = load_g(A.src, t, so, nsv);
    EData B = load_e(e_b, eidx2, enorm, evec, es);

    int cur_dst = -1;
    float as = 0.0f, av0 = 0.0f, av1 = 0.0f, av2 = 0.0f;

#pragma unroll 2
    for (int i = beg; i < end; ++i) {
        // stage i+1: issue src gathers for B
        GData GB = load_g(B.src, t, so, nsv);
        // stage i+2: e-indexed loads
        int i2 = (i + 2 < end) ? i + 2 : end - 1;
        int e_c = perm[i2];
        EData C = load_e(e_c, eidx2, enorm, evec, es);

        // stage i: compute with A / GA
        if (A.dst != cur_dst) {
            if (cur_dst >= 0) {
                atomicAdd(&out_s[(long)cur_dst * ND + t], as);
                atomicAdd(&out_v[(long)cur_dst * 384 + 0 * ND + t], av0);
                atomicAdd(&out_v[(long)cur_dst * 384 + 1 * ND + t], av1);
                atomicAdd(&out_v[(long)cur_dst * 384 + 2 * ND + t], av2);
            }
            cur_dst = A.dst;
            as = 0.0f; av0 = 0.0f; av1 = 0.0f; av2 = 0.0f;
        }
        float f0 = bfr[0], f1 = bfr[1], f2 = bfr[2];
#pragma unroll
        for (int k = 0; k < ESZ; ++k) {
            f0 += A.er[k] * wf[k][0];
            f1 += A.er[k] * wf[k][1];
            f2 += A.er[k] * wf[k][2];
        }
        float fcv = (A.nrm < CUT) ? 0.5f * (__cosf(PI_F * A.nrm * (1.0f / CUT)) + 1.0f)
                                  : 0.0f;
        f0 *= fcv * GA.so0;   // gate_nodes
        f1 *= fcv * GA.so1;   // gate_edges
        f2 *= fcv * GA.so2;   // messages_scalar
        as  += f2;
        av0 += GA.nv0 * f0 + f1 * A.ev0;
        av1 += GA.nv1 * f0 + f1 * A.ev1;
        av2 += GA.nv2 * f0 + f1 * A.ev2;

        // rotate
        A = B; GA = GB; B = C;
    }
    // final flush
    atomicAdd(&out_s[(long)cur_dst * ND + t], as);
    atomicAdd(&out_v[(long)cur_dst * 384 + 0 * ND + t], av0);
    atomicAdd(&out_v[(long)cur_dst * 384 + 1 * ND + t], av1);
    atomicAdd(&out_v[(long)cur_dst * 384 + 2 * ND + t], av2);
}

// ---------------------------------------------------------------------------
// Kernel 3: node update (in place on out_s / out_v)
// ---------------------------------------------------------------------------
#define NPB_D 8
__global__ __launch_bounds__(128) void k_update(
    const float* __restrict__ WU, const float* __restrict__ WV,
    const float* __restrict__ Wa1, const float* __restrict__ ba1,
    const float* __restrict__ Wa2, const float* __restrict__ ba2,
    float* __restrict__ out_s, float* __restrict__ out_v) {
    __shared__ float ls_s[NPB_D][ND];
    __shared__ float ls_v[NPB_D][3 * ND];
    __shared__ float ls_q[NPB_D][ND];
    __shared__ float ls_h[NPB_D][ND];
    const int t = threadIdx.x;
    const int n0 = blockIdx.x * NPB_D;

    for (int nn = 0; nn < NPB_D; ++nn) {
        int node = n0 + nn;
        if (node < NN) {
            ls_s[nn][t] = out_s[(long)node * ND + t];
            for (int ax = 0; ax < 3; ++ax)
                ls_v[nn][ax * ND + t] = out_v[(long)node * 384 + ax * ND + t];
        } else {
            ls_s[nn][t] = 0.0f;
            for (int ax = 0; ax < 3; ++ax) ls_v[nn][ax * ND + t] = 0.0f;
        }
    }
    __syncthreads();

    float Uv[NPB_D][3] = {}, Vv[NPB_D][3] = {};
    for (int d = 0; d < ND; d += 4) {
        float wu[4], wv[4];
        for (int q = 0; q < 4; ++q) {
            wu[q] = WU[(d + q) * ND + t];
            wv[q] = WV[(d + q) * ND + t];
        }
        for (int nn = 0; nn < NPB_D; ++nn)
            for (int ax = 0; ax < 3; ++ax) {
                float4 vx = *reinterpret_cast<const float4*>(&ls_v[nn][ax * ND + d]);
                Uv[nn][ax] += vx.x * wu[0] + vx.y * wu[1] + vx.z * wu[2] + vx.w * wu[3];
                Vv[nn][ax] += vx.x * wv[0] + vx.y * wv[1] + vx.z * wv[2] + vx.w * wv[3];
            }
    }
    for (int nn = 0; nn < NPB_D; ++nn)
        ls_q[nn][t] = Vv[nn][0] * Vv[nn][0] + Vv[nn][1] * Vv[nn][1] + Vv[nn][2] * Vv[nn][2];
    __syncthreads();

    float hid[NPB_D];
    {
        float b = ba1[t];
        for (int nn = 0; nn < NPB_D; ++nn) hid[nn] = b;
    }
    for (int k = 0; k < ND; k += 4) {
        float w[4];
        for (int q = 0; q < 4; ++q) w[q] = Wa1[(k + q) * ND + t];
        for (int nn = 0; nn < NPB_D; ++nn) {
            float4 x = *reinterpret_cast<const float4*>(&ls_s[nn][k]);
            hid[nn] += x.x * w[0] + x.y * w[1] + x.z * w[2] + x.w * w[3];
        }
    }
    for (int k = 0; k < ND; k += 4) {
        float w[4];
        for (int q = 0; q < 4; ++q) w[q] = Wa1[(ND + k + q) * ND + t];
        for (int nn = 0; nn < NPB_D; ++nn) {
            float4 x = *reinterpret_cast<const float4*>(&ls_q[nn][k]);
            hid[nn] += x.x * w[0] + x.y * w[1] + x.z * w[2] + x.w * w[3];
        }
    }
    for (int nn = 0; nn < NPB_D; ++nn) ls_h[nn][t] = silu_f(hid[nn]);
    __syncthreads();

    float a[NPB_D][3];
    for (int c = 0; c < 3; ++c) {
        float b = ba2[c * ND + t];
        for (int nn = 0; nn < NPB_D; ++nn) a[nn][c] = b;
    }
    for (int k = 0; k < ND; k += 4) {
        float w[4][3];
        for (int q = 0; q < 4; ++q)
            for (int c = 0; c < 3; ++c)
                w[q][c] = Wa2[(k + q) * 384 + c * ND + t];
        for (int nn = 0; nn < NPB_D; ++nn) {
            float4 h = *reinterpret_cast<const float4*>(&ls_h[nn][k]);
            for (int c = 0; c < 3; ++c)
                a[nn][c] += h.x * w[0][c] + h.y * w[1][c] + h.z * w[2][c] + h.w * w[3][c];
        }
    }

    for (int nn = 0; nn < NPB_D; ++nn) {
        int node = n0 + nn;
        if (node >= NN) continue;
        float ip = Uv[nn][0] * Vv[nn][0] + Uv[nn][1] * Vv[nn][1] + Uv[nn][2] * Vv[nn][2];
        out_s[(long)node * ND + t] = ls_s[nn][t] + a[nn][0] + a[nn][1] * ip;
        for (int ax = 0; ax < 3; ++ax)
            out_v[(long)node * 384 + ax * ND + t] =
                ls_v[nn][ax * ND + t] + a[nn][2] * Uv[nn][ax];
    }
}

// ---------------------------------------------------------------------------
extern "C" void kernel_launch(void* const* d_in, const int* in_sizes, int n_in,
                              void* d_out, int out_size, void* d_ws, size_t ws_size,
                              hipStream_t stream) {
    const float* ns    = (const float*)d_in[0];
    const float* nsv   = (const float*)d_in[1];
    const float* es    = (const float*)d_in[2];
    const float* evec  = (const float*)d_in[3];
    const float* enorm = (const float*)d_in[4];
    const int*   eidx  = (const int*)d_in[5];
    const float* Wf    = (const float*)d_in[6];
    const float* bf    = (const float*)d_in[7];
    const float* Wm1   = (const float*)d_in[8];
    const float* bm1   = (const float*)d_in[9];
    const float* Wm2   = (const float*)d_in[10];
    const float* bm2   = (const float*)d_in[11];
    const float* WU    = (const float*)d_in[12];
    const float* WV    = (const float*)d_in[13];
    const float* Wa1   = (const float*)d_in[14];
    const float* ba1   = (const float*)d_in[15];
    const float* Wa2   = (const float*)d_in[16];
    const float* ba2   = (const float*)d_in[17];

    float* out_s = (float*)d_out;
    float* out_v = out_s + (size_t)NN * ND;

    // workspace layout
    char* w = (char*)d_ws;
    float* so     = (float*)w;                 w += (size_t)NN * 384 * sizeof(float);
    int*   counts = (int*)w;                   w += (size_t)NN * sizeof(int);
    int*   offs   = (int*)w;                   w += (size_t)(NN + 1) * sizeof(int);
    int*   cursor = (int*)w;                   w += (size_t)NN * sizeof(int);
    int*   perm   = (int*)w;                   w += (size_t)NE * sizeof(int);

    hipMemsetAsync(counts, 0, (size_t)NN * sizeof(int), stream);
    k_hist<<<(NE + 255) / 256, 256, 0, stream>>>(eidx, counts);
    k_scan<<<1, SCAN_T, 0, stream>>>(counts, offs, cursor);
    k_scatter<<<(NE + 255) / 256, 256, 0, stream>>>(eidx, cursor, perm);
    k_node_mlp<<<(NN + NPB_A - 1) / NPB_A, 128, 0, stream>>>(ns, Wm1, bm1, Wm2, bm2, so);
    k_init<<<10000, 256, 0, stream>>>((const float4*)ns, (const float4*)nsv,
                                      (float4*)out_s, (float4*)out_v);
    k_edge2<<<NGRP / 2, 256, 0, stream>>>(es, evec, enorm, (const int2*)eidx, perm,
                                          Wf, bf, so, nsv, out_s, out_v);
    k_update<<<(NN + NPB_D - 1) / NPB_D, 128, 0, stream>>>(WU, WV, Wa1, ba1, Wa2, ba2,
                                                           out_s, out_v);
}

// Round 4
// 869.165 us; speedup vs baseline: 1.5709x; 1.1257x over previous
//
#include <hip/hip_runtime.h>

#define ND 128          // NODE_SIZE
#define ESZ 20          // EDGE_SIZE
#define NN 20000        // N_NODES
#define NE 600000       // N_EDGES
#define PI_F 3.14159265358979323846f
#define CUT 5.0f

__device__ __forceinline__ float silu_f(float x) { return x / (1.0f + __expf(-x)); }

// bf16 helpers (round-to-nearest-even pack, shift unpack)
__device__ __forceinline__ unsigned short f2bf(float x) {
    unsigned u = __float_as_uint(x);
    unsigned r = (u + 0x7FFFu + ((u >> 16) & 1u)) >> 16;
    return (unsigned short)r;
}
__device__ __forceinline__ float bf2f(unsigned short h) {
    return __uint_as_float(((unsigned)h) << 16);
}

// ---------------------------------------------------------------------------
// Kernel 0: out_s = ns, out_v = nsv; also pack nsv -> bf16 table nvh
// ---------------------------------------------------------------------------
__global__ __launch_bounds__(256) void k_init(const float4* __restrict__ ns,
                                              const float4* __restrict__ nsv,
                                              float4* __restrict__ outs,
                                              float4* __restrict__ outv,
                                              ushort4* __restrict__ nvh4) {
    long i = (long)blockIdx.x * 256 + threadIdx.x;
    const long S4 = (long)NN * ND / 4;
    const long V4 = (long)NN * 3 * ND / 4;
    if (i < S4) {
        outs[i] = ns[i];
    } else {
        long j = i - S4;
        if (j < V4) {
            float4 v = nsv[j];
            outv[j] = v;
            ushort4 h;
            h.x = f2bf(v.x); h.y = f2bf(v.y); h.z = f2bf(v.z); h.w = f2bf(v.w);
            nvh4[j] = h;
        }
    }
}

// ---------------------------------------------------------------------------
// Kernel 1: scalar_output (bf16) = silu(ns @ Wm1 + bm1) @ Wm2 + bm2
// ---------------------------------------------------------------------------
#define NPB_A 16
__global__ __launch_bounds__(128) void k_node_mlp(
    const float* __restrict__ ns,
    const float* __restrict__ Wm1, const float* __restrict__ bm1,
    const float* __restrict__ Wm2, const float* __restrict__ bm2,
    unsigned short* __restrict__ soh) {
    __shared__ float ls_ns[NPB_A][ND];
    __shared__ float ls_h[NPB_A][ND];
    const int t = threadIdx.x;
    const int n0 = blockIdx.x * NPB_A;

    for (int nn = 0; nn < NPB_A; ++nn) {
        int node = n0 + nn;
        ls_ns[nn][t] = (node < NN) ? ns[(long)node * ND + t] : 0.0f;
    }
    __syncthreads();

    float hid[NPB_A];
    {
        float b = bm1[t];
        for (int nn = 0; nn < NPB_A; ++nn) hid[nn] = b;
    }
    for (int k = 0; k < ND; k += 4) {
        float w0 = Wm1[(k + 0) * ND + t];
        float w1 = Wm1[(k + 1) * ND + t];
        float w2 = Wm1[(k + 2) * ND + t];
        float w3 = Wm1[(k + 3) * ND + t];
        for (int nn = 0; nn < NPB_A; ++nn) {
            float4 x = *reinterpret_cast<const float4*>(&ls_ns[nn][k]);
            hid[nn] += x.x * w0 + x.y * w1 + x.z * w2 + x.w * w3;
        }
    }
    for (int nn = 0; nn < NPB_A; ++nn) ls_h[nn][t] = silu_f(hid[nn]);
    __syncthreads();

    float acc[NPB_A][3];
    for (int c = 0; c < 3; ++c) {
        float b = bm2[c * ND + t];
        for (int nn = 0; nn < NPB_A; ++nn) acc[nn][c] = b;
    }
    for (int k = 0; k < ND; k += 4) {
        float w[4][3];
        for (int q = 0; q < 4; ++q)
            for (int c = 0; c < 3; ++c)
                w[q][c] = Wm2[(k + q) * 384 + c * ND + t];
        for (int nn = 0; nn < NPB_A; ++nn) {
            float4 h = *reinterpret_cast<const float4*>(&ls_h[nn][k]);
            for (int c = 0; c < 3; ++c)
                acc[nn][c] += h.x * w[0][c] + h.y * w[1][c] + h.z * w[2][c] + h.w * w[3][c];
        }
    }
    for (int nn = 0; nn < NPB_A; ++nn) {
        int node = n0 + nn;
        if (node < NN)
            for (int c = 0; c < 3; ++c)
                soh[(long)node * 384 + c * ND + t] = f2bf(acc[nn][c]);
    }
}

// ---------------------------------------------------------------------------
// CSR build: histogram by dst, prefix scan, scatter permutation
// ---------------------------------------------------------------------------
__global__ __launch_bounds__(256) void k_hist(const int* __restrict__ eidx,
                                              int* __restrict__ counts) {
    int e = blockIdx.x * 256 + threadIdx.x;
    if (e < NE) atomicAdd(&counts[eidx[2 * e + 1]], 1);
}

#define SCAN_T 1024
__global__ __launch_bounds__(SCAN_T) void k_scan(const int* __restrict__ counts,
                                                 int* __restrict__ offsets,
                                                 int* __restrict__ cursor) {
    __shared__ int part[SCAN_T];
    const int t = threadIdx.x;
    const int CPT = (NN + SCAN_T - 1) / SCAN_T;
    const int base = t * CPT;
    int sum = 0;
    for (int i = 0; i < CPT; ++i) {
        int idx = base + i;
        if (idx < NN) sum += counts[idx];
    }
    part[t] = sum;
    __syncthreads();
    for (int off = 1; off < SCAN_T; off <<= 1) {
        int v = (t >= off) ? part[t - off] : 0;
        __syncthreads();
        part[t] += v;
        __syncthreads();
    }
    int run = (t == 0) ? 0 : part[t - 1];
    for (int i = 0; i < CPT; ++i) {
        int idx = base + i;
        if (idx < NN) {
            offsets[idx] = run;
            cursor[idx] = run;
            run += counts[idx];
        }
    }
    if (t == SCAN_T - 1) offsets[NN] = run;
}

__global__ __launch_bounds__(256) void k_scatter(const int* __restrict__ eidx,
                                                 int* __restrict__ cursor,
                                                 int* __restrict__ perm) {
    int e = blockIdx.x * 256 + threadIdx.x;
    if (e < NE) {
        int pos = atomicAdd(&cursor[eidx[2 * e + 1]], 1);
        perm[pos] = e;
    }
}

// ---------------------------------------------------------------------------
// Kernel 2: edge-parallel segmented reduction, dst-sorted runs.
// Per-edge uniform data (perm, eidx, enorm, evec, es row) loaded via
// wave-uniform (readfirstlane) addresses -> SGPRs / scalar pipe.
// Per-channel gathers from bf16 tables soh/nvh. Next-edge prefetch.
// ---------------------------------------------------------------------------
#define NGRP 8192
#define RUN ((NE + NGRP - 1) / NGRP)   // 74

__global__ __launch_bounds__(256, 4) void k_edge3(
    const float* __restrict__ es, const float* __restrict__ evec,
    const float* __restrict__ enorm, const int* __restrict__ eidx,
    const int* __restrict__ perm,
    const float* __restrict__ Wf, const float* __restrict__ bf,
    const unsigned short* __restrict__ soh, const unsigned short* __restrict__ nvh,
    float* __restrict__ out_s, float* __restrict__ out_v) {
    const int t = threadIdx.x & 127;
    const int grp = blockIdx.x * 2 + (threadIdx.x >> 7);
    const int beg = grp * RUN;
    const int end = (beg + RUN < NE) ? beg + RUN : NE;
    if (beg >= end) return;

    // Wf columns for channels t, t+128, t+256 in registers (60 VGPR)
    float wf[ESZ][3];
#pragma unroll
    for (int k = 0; k < ESZ; ++k)
        for (int c = 0; c < 3; ++c)
            wf[k][c] = Wf[k * 384 + c * ND + t];
    float bfr[3];
    for (int c = 0; c < 3; ++c) bfr[c] = bf[c * ND + t];

    // ---- prefetch edge[beg] ----
    int eA = __builtin_amdgcn_readfirstlane(perm[beg]);
    int srcA = __builtin_amdgcn_readfirstlane(eidx[2 * eA]);
    int dstA = __builtin_amdgcn_readfirstlane(eidx[2 * eA + 1]);
    float nrmA = enorm[eA];
    float evA0 = evec[3 * eA + 0], evA1 = evec[3 * eA + 1], evA2 = evec[3 * eA + 2];
    float erA[ESZ];
#pragma unroll
    for (int k = 0; k < ESZ; ++k) erA[k] = es[(long)eA * ESZ + k];
    unsigned short gA0, gA1, gA2, hA0, hA1, hA2;
    {
        const unsigned short* sp = soh + (long)srcA * 384;
        gA0 = sp[t]; gA1 = sp[ND + t]; gA2 = sp[2 * ND + t];
        const unsigned short* np = nvh + (long)srcA * 384;
        hA0 = np[t]; hA1 = np[ND + t]; hA2 = np[2 * ND + t];
    }

    int cur_dst = -1;
    float as = 0.0f, av0 = 0.0f, av1 = 0.0f, av2 = 0.0f;

#pragma unroll 2
    for (int i = beg; i < end; ++i) {
        // ---- prefetch edge[i+1] ----
        int ip = (i + 1 < end) ? i + 1 : end - 1;
        int eB = __builtin_amdgcn_readfirstlane(perm[ip]);
        int srcB = __builtin_amdgcn_readfirstlane(eidx[2 * eB]);
        int dstB = __builtin_amdgcn_readfirstlane(eidx[2 * eB + 1]);
        float nrmB = enorm[eB];
        float evB0 = evec[3 * eB + 0], evB1 = evec[3 * eB + 1], evB2 = evec[3 * eB + 2];
        float erB[ESZ];
#pragma unroll
        for (int k = 0; k < ESZ; ++k) erB[k] = es[(long)eB * ESZ + k];
        unsigned short gB0, gB1, gB2, hB0, hB1, hB2;
        {
            const unsigned short* sp = soh + (long)srcB * 384;
            gB0 = sp[t]; gB1 = sp[ND + t]; gB2 = sp[2 * ND + t];
            const unsigned short* np = nvh + (long)srcB * 384;
            hB0 = np[t]; hB1 = np[ND + t]; hB2 = np[2 * ND + t];
        }

        // ---- compute edge[i] ----
        if (dstA != cur_dst) {
            if (cur_dst >= 0) {
                atomicAdd(&out_s[(long)cur_dst * ND + t], as);
                atomicAdd(&out_v[(long)cur_dst * 384 + 0 * ND + t], av0);
                atomicAdd(&out_v[(long)cur_dst * 384 + 1 * ND + t], av1);
                atomicAdd(&out_v[(long)cur_dst * 384 + 2 * ND + t], av2);
            }
            cur_dst = dstA;
            as = 0.0f; av0 = 0.0f; av1 = 0.0f; av2 = 0.0f;
        }
        float f0 = bfr[0], f1 = bfr[1], f2 = bfr[2];
#pragma unroll
        for (int k = 0; k < ESZ; ++k) {
            f0 += erA[k] * wf[k][0];
            f1 += erA[k] * wf[k][1];
            f2 += erA[k] * wf[k][2];
        }
        float fcv = (nrmA < CUT) ? 0.5f * (__cosf(PI_F * nrmA * (1.0f / CUT)) + 1.0f)
                                 : 0.0f;
        f0 *= fcv * bf2f(gA0);   // gate_nodes
        f1 *= fcv * bf2f(gA1);   // gate_edges
        f2 *= fcv * bf2f(gA2);   // messages_scalar
        as  += f2;
        av0 += bf2f(hA0) * f0 + f1 * evA0;
        av1 += bf2f(hA1) * f0 + f1 * evA1;
        av2 += bf2f(hA2) * f0 + f1 * evA2;

        // ---- rotate ----
        srcA = srcB; dstA = dstB; nrmA = nrmB;
        evA0 = evB0; evA1 = evB1; evA2 = evB2;
#pragma unroll
        for (int k = 0; k < ESZ; ++k) erA[k] = erB[k];
        gA0 = gB0; gA1 = gB1; gA2 = gB2;
        hA0 = hB0; hA1 = hB1; hA2 = hB2;
    }
    atomicAdd(&out_s[(long)cur_dst * ND + t], as);
    atomicAdd(&out_v[(long)cur_dst * 384 + 0 * ND + t], av0);
    atomicAdd(&out_v[(long)cur_dst * 384 + 1 * ND + t], av1);
    atomicAdd(&out_v[(long)cur_dst * 384 + 2 * ND + t], av2);
}

// ---------------------------------------------------------------------------
// Kernel 3: node update (in place on out_s / out_v)
// ---------------------------------------------------------------------------
#define NPB_D 8
__global__ __launch_bounds__(128) void k_update(
    const float* __restrict__ WU, const float* __restrict__ WV,
    const float* __restrict__ Wa1, const float* __restrict__ ba1,
    const float* __restrict__ Wa2, const float* __restrict__ ba2,
    float* __restrict__ out_s, float* __restrict__ out_v) {
    __shared__ float ls_s[NPB_D][ND];
    __shared__ float ls_v[NPB_D][3 * ND];
    __shared__ float ls_q[NPB_D][ND];
    __shared__ float ls_h[NPB_D][ND];
    const int t = threadIdx.x;
    const int n0 = blockIdx.x * NPB_D;

    for (int nn = 0; nn < NPB_D; ++nn) {
        int node = n0 + nn;
        if (node < NN) {
            ls_s[nn][t] = out_s[(long)node * ND + t];
            for (int ax = 0; ax < 3; ++ax)
                ls_v[nn][ax * ND + t] = out_v[(long)node * 384 + ax * ND + t];
        } else {
            ls_s[nn][t] = 0.0f;
            for (int ax = 0; ax < 3; ++ax) ls_v[nn][ax * ND + t] = 0.0f;
        }
    }
    __syncthreads();

    float Uv[NPB_D][3] = {}, Vv[NPB_D][3] = {};
    for (int d = 0; d < ND; d += 4) {
        float wu[4], wv[4];
        for (int q = 0; q < 4; ++q) {
            wu[q] = WU[(d + q) * ND + t];
            wv[q] = WV[(d + q) * ND + t];
        }
        for (int nn = 0; nn < NPB_D; ++nn)
            for (int ax = 0; ax < 3; ++ax) {
                float4 vx = *reinterpret_cast<const float4*>(&ls_v[nn][ax * ND + d]);
                Uv[nn][ax] += vx.x * wu[0] + vx.y * wu[1] + vx.z * wu[2] + vx.w * wu[3];
                Vv[nn][ax] += vx.x * wv[0] + vx.y * wv[1] + vx.z * wv[2] + vx.w * wv[3];
            }
    }
    for (int nn = 0; nn < NPB_D; ++nn)
        ls_q[nn][t] = Vv[nn][0] * Vv[nn][0] + Vv[nn][1] * Vv[nn][1] + Vv[nn][2] * Vv[nn][2];
    __syncthreads();

    float hid[NPB_D];
    {
        float b = ba1[t];
        for (int nn = 0; nn < NPB_D; ++nn) hid[nn] = b;
    }
    for (int k = 0; k < ND; k += 4) {
        float w[4];
        for (int q = 0; q < 4; ++q) w[q] = Wa1[(k + q) * ND + t];
        for (int nn = 0; nn < NPB_D; ++nn) {
            float4 x = *reinterpret_cast<const float4*>(&ls_s[nn][k]);
            hid[nn] += x.x * w[0] + x.y * w[1] + x.z * w[2] + x.w * w[3];
        }
    }
    for (int k = 0; k < ND; k += 4) {
        float w[4];
        for (int q = 0; q < 4; ++q) w[q] = Wa1[(ND + k + q) * ND + t];
        for (int nn = 0; nn < NPB_D; ++nn) {
            float4 x = *reinterpret_cast<const float4*>(&ls_q[nn][k]);
            hid[nn] += x.x * w[0] + x.y * w[1] + x.z * w[2] + x.w * w[3];
        }
    }
    for (int nn = 0; nn < NPB_D; ++nn) ls_h[nn][t] = silu_f(hid[nn]);
    __syncthreads();

    float a[NPB_D][3];
    for (int c = 0; c < 3; ++c) {
        float b = ba2[c * ND + t];
        for (int nn = 0; nn < NPB_D; ++nn) a[nn][c] = b;
    }
    for (int k = 0; k < ND; k += 4) {
        float w[4][3];
        for (int q = 0; q < 4; ++q)
            for (int c = 0; c < 3; ++c)
                w[q][c] = Wa2[(k + q) * 384 + c * ND + t];
        for (int nn = 0; nn < NPB_D; ++nn) {
            float4 h = *reinterpret_cast<const float4*>(&ls_h[nn][k]);
            for (int c = 0; c < 3; ++c)
                a[nn][c] += h.x * w[0][c] + h.y * w[1][c] + h.z * w[2][c] + h.w * w[3][c];
        }
    }

    for (int nn = 0; nn < NPB_D; ++nn) {
        int node = n0 + nn;
        if (node >= NN) continue;
        float ip = Uv[nn][0] * Vv[nn][0] + Uv[nn][1] * Vv[nn][1] + Uv[nn][2] * Vv[nn][2];
        out_s[(long)node * ND + t] = ls_s[nn][t] + a[nn][0] + a[nn][1] * ip;
        for (int ax = 0; ax < 3; ++ax)
            out_v[(long)node * 384 + ax * ND + t] =
                ls_v[nn][ax * ND + t] + a[nn][2] * Uv[nn][ax];
    }
}

// ---------------------------------------------------------------------------
extern "C" void kernel_launch(void* const* d_in, const int* in_sizes, int n_in,
                              void* d_out, int out_size, void* d_ws, size_t ws_size,
                              hipStream_t stream) {
    const float* ns    = (const float*)d_in[0];
    const float* nsv   = (const float*)d_in[1];
    const float* es    = (const float*)d_in[2];
    const float* evec  = (const float*)d_in[3];
    const float* enorm = (const float*)d_in[4];
    const int*   eidx  = (const int*)d_in[5];
    const float* Wf    = (const float*)d_in[6];
    const float* bf    = (const float*)d_in[7];
    const float* Wm1   = (const float*)d_in[8];
    const float* bm1   = (const float*)d_in[9];
    const float* Wm2   = (const float*)d_in[10];
    const float* bm2   = (const float*)d_in[11];
    const float* WU    = (const float*)d_in[12];
    const float* WV    = (const float*)d_in[13];
    const float* Wa1   = (const float*)d_in[14];
    const float* ba1   = (const float*)d_in[15];
    const float* Wa2   = (const float*)d_in[16];
    const float* ba2   = (const float*)d_in[17];

    float* out_s = (float*)d_out;
    float* out_v = out_s + (size_t)NN * ND;

    // workspace layout
    char* w = (char*)d_ws;
    unsigned short* soh = (unsigned short*)w;  w += (size_t)NN * 384 * sizeof(unsigned short);
    unsigned short* nvh = (unsigned short*)w;  w += (size_t)NN * 384 * sizeof(unsigned short);
    int* counts = (int*)w;                     w += (size_t)NN * sizeof(int);
    int* offs   = (int*)w;                     w += (size_t)(NN + 1) * sizeof(int);
    int* cursor = (int*)w;                     w += (size_t)NN * sizeof(int);
    int* perm   = (int*)w;                     w += (size_t)NE * sizeof(int);

    hipMemsetAsync(counts, 0, (size_t)NN * sizeof(int), stream);
    k_hist<<<(NE + 255) / 256, 256, 0, stream>>>(eidx, counts);
    k_scan<<<1, SCAN_T, 0, stream>>>(counts, offs, cursor);
    k_scatter<<<(NE + 255) / 256, 256, 0, stream>>>(eidx, cursor, perm);
    k_node_mlp<<<(NN + NPB_A - 1) / NPB_A, 128, 0, stream>>>(ns, Wm1, bm1, Wm2, bm2, soh);
    k_init<<<10000, 256, 0, stream>>>((const float4*)ns, (const float4*)nsv,
                                      (float4*)out_s, (float4*)out_v, (ushort4*)nvh);
    k_edge3<<<NGRP / 2, 256, 0, stream>>>(es, evec, enorm, eidx, perm,
                                          Wf, bf, soh, nvh, out_s, out_v);
    k_update<<<(NN + NPB_D - 1) / NPB_D, 128, 0, stream>>>(WU, WV, Wa1, ba1, Wa2, ba2,
                                                           out_s, out_v);
}

// Round 5
// 720.068 us; speedup vs baseline: 1.8962x; 1.2071x over previous
//
#include <hip/hip_runtime.h>

#define ND 128          // NODE_SIZE
#define ESZ 20          // EDGE_SIZE
#define NN 20000        // N_NODES
#define NE 600000       // N_EDGES
#define PI_F 3.14159265358979323846f
#define CUT 5.0f

using short8 = __attribute__((ext_vector_type(8))) short;   // 8 bf16 (4 VGPR)
using f32x4  = __attribute__((ext_vector_type(4))) float;   // MFMA C/D

__device__ __forceinline__ float silu_f(float x) { return x / (1.0f + __expf(-x)); }

__device__ __forceinline__ unsigned short f2bf(float x) {
    unsigned u = __float_as_uint(x);
    unsigned r = (u + 0x7FFFu + ((u >> 16) & 1u)) >> 16;
    return (unsigned short)r;
}
__device__ __forceinline__ float bf2f(unsigned short h) {
    return __uint_as_float(((unsigned)h) << 16);
}

// ---------------------------------------------------------------------------
// k_prep: out_s=ns, out_v=nsv, nsb=bf16(ns), nvh=bf16(nsv)
// ---------------------------------------------------------------------------
__global__ __launch_bounds__(256) void k_prep(const float4* __restrict__ ns4,
                                              const float4* __restrict__ nsv4,
                                              float4* __restrict__ outs4,
                                              float4* __restrict__ outv4,
                                              ushort4* __restrict__ nsb4,
                                              ushort4* __restrict__ nvh4) {
    long i = (long)blockIdx.x * 256 + threadIdx.x;   // 0 .. 1,920,000
    const long S4 = (long)NN * ND / 4;               // 640,000
    if (i < S4) {
        float4 v = ns4[i];
        outs4[i] = v;
        ushort4 h; h.x = f2bf(v.x); h.y = f2bf(v.y); h.z = f2bf(v.z); h.w = f2bf(v.w);
        nsb4[i] = h;
    }
    float4 w = nsv4[i];
    outv4[i] = w;
    ushort4 h2; h2.x = f2bf(w.x); h2.y = f2bf(w.y); h2.z = f2bf(w.z); h2.w = f2bf(w.w);
    nvh4[i] = h2;
}

// ---------------------------------------------------------------------------
// k_packw: pack fp32 weights (row-major K x N) into B-fragment layout bf16.
// dst = ((nt*(K/32)+kb)*64 + lane)*8 + j  with lane = ((k>>3)&3)*16 + (n&15)
// ---------------------------------------------------------------------------
__device__ __forceinline__ void pack_w(const float* __restrict__ W,
                                       unsigned short* __restrict__ P,
                                       int s, int K, int N) {
    int k = s / N, n = s - k * N;
    int dst = ((((n >> 4) * (K >> 5) + (k >> 5)) * 64) +
               (((k >> 3) & 3) << 4) + (n & 15)) * 8 + (k & 7);
    P[dst] = f2bf(W[s]);
}

__global__ __launch_bounds__(256) void k_packw(
    const float* __restrict__ Wm1, const float* __restrict__ Wm2,
    const float* __restrict__ WU, const float* __restrict__ WV,
    const float* __restrict__ Wa1, const float* __restrict__ Wa2,
    unsigned short* __restrict__ p1, unsigned short* __restrict__ p2,
    unsigned short* __restrict__ pU, unsigned short* __restrict__ pV,
    unsigned short* __restrict__ pa1, unsigned short* __restrict__ pa2) {
    int i = blockIdx.x * 256 + threadIdx.x;
    if      (i <  16384) pack_w(Wm1, p1, i,          128, 128);
    else if (i <  65536) pack_w(Wm2, p2, i - 16384,  128, 384);
    else if (i <  81920) pack_w(WU,  pU, i - 65536,  128, 128);
    else if (i <  98304) pack_w(WV,  pV, i - 81920,  128, 128);
    else if (i < 131072) pack_w(Wa1, pa1, i - 98304, 256, 128);
    else if (i < 180224) pack_w(Wa2, pa2, i - 131072,128, 384);
}

// ---------------------------------------------------------------------------
// k_mlp: soh(bf16) = silu(nsb @ Wm1 + bm1) @ Wm2 + bm2, one wave per 16 nodes
// ---------------------------------------------------------------------------
__global__ __launch_bounds__(256) void k_mlp(
    const unsigned short* __restrict__ nsb,
    const unsigned short* __restrict__ Wm1p, const float* __restrict__ bm1,
    const unsigned short* __restrict__ Wm2p, const float* __restrict__ bm2,
    unsigned short* __restrict__ soh) {
    const int lane = threadIdx.x & 63;
    const int wv = threadIdx.x >> 6;
    const int wid = blockIdx.x * 4 + wv;
    const int m0 = wid * 16;
    if (m0 >= NN) return;
    const int ml = lane & 15, q = lane >> 4;
    __shared__ unsigned short lsh[4][16][136];

    short8 a1[4];
#pragma unroll
    for (int kb = 0; kb < 4; ++kb)
        a1[kb] = *(const short8*)(nsb + (long)(m0 + ml) * ND + kb * 32 + q * 8);

#pragma unroll
    for (int nt = 0; nt < 8; ++nt) {
        float b = bm1[nt * 16 + ml];
        f32x4 acc = {b, b, b, b};
#pragma unroll
        for (int kb = 0; kb < 4; ++kb) {
            short8 bf = *(const short8*)(Wm1p + ((nt * 4 + kb) * 64 + lane) * 8);
            acc = __builtin_amdgcn_mfma_f32_16x16x32_bf16(a1[kb], bf, acc, 0, 0, 0);
        }
#pragma unroll
        for (int r = 0; r < 4; ++r)
            lsh[wv][q * 4 + r][nt * 16 + ml] = f2bf(silu_f(acc[r]));
    }

    short8 a2[4];
#pragma unroll
    for (int kb = 0; kb < 4; ++kb)
        a2[kb] = *(const short8*)(&lsh[wv][ml][kb * 32 + q * 8]);

#pragma unroll
    for (int nt = 0; nt < 24; ++nt) {
        float b = bm2[nt * 16 + ml];
        f32x4 acc = {b, b, b, b};
#pragma unroll
        for (int kb = 0; kb < 4; ++kb) {
            short8 bf = *(const short8*)(Wm2p + ((nt * 4 + kb) * 64 + lane) * 8);
            acc = __builtin_amdgcn_mfma_f32_16x16x32_bf16(a2[kb], bf, acc, 0, 0, 0);
        }
#pragma unroll
        for (int r = 0; r < 4; ++r)
            soh[(long)(m0 + q * 4 + r) * 384 + nt * 16 + ml] = f2bf(acc[r]);
    }
}

// ---------------------------------------------------------------------------
// CSR build
// ---------------------------------------------------------------------------
__global__ __launch_bounds__(256) void k_hist(const int* __restrict__ eidx,
                                              int* __restrict__ counts) {
    int e = blockIdx.x * 256 + threadIdx.x;
    if (e < NE) atomicAdd(&counts[eidx[2 * e + 1]], 1);
}

#define SCAN_T 1024
__global__ __launch_bounds__(SCAN_T) void k_scan(const int* __restrict__ counts,
                                                 int* __restrict__ offsets,
                                                 int* __restrict__ cursor) {
    __shared__ int part[SCAN_T];
    const int t = threadIdx.x;
    const int CPT = (NN + SCAN_T - 1) / SCAN_T;
    const int base = t * CPT;
    int sum = 0;
    for (int i = 0; i < CPT; ++i) {
        int idx = base + i;
        if (idx < NN) sum += counts[idx];
    }
    part[t] = sum;
    __syncthreads();
    for (int off = 1; off < SCAN_T; off <<= 1) {
        int v = (t >= off) ? part[t - off] : 0;
        __syncthreads();
        part[t] += v;
        __syncthreads();
    }
    int run = (t == 0) ? 0 : part[t - 1];
    for (int i = 0; i < CPT; ++i) {
        int idx = base + i;
        if (idx < NN) {
            offsets[idx] = run;
            cursor[idx] = run;
            run += counts[idx];
        }
    }
    if (t == SCAN_T - 1) offsets[NN] = run;
}

__global__ __launch_bounds__(256) void k_scatter(const int* __restrict__ eidx,
                                                 int* __restrict__ cursor,
                                                 int* __restrict__ perm) {
    int e = blockIdx.x * 256 + threadIdx.x;
    if (e < NE) {
        int pos = atomicAdd(&cursor[eidx[2 * e + 1]], 1);
        perm[pos] = e;
    }
}

// ---------------------------------------------------------------------------
// k_edge3: unchanged from round 4 (segmented reduction, SGPR edge data,
// bf16 gathers, next-edge prefetch)
// ---------------------------------------------------------------------------
#define NGRP 8192
#define RUN ((NE + NGRP - 1) / NGRP)   // 74

__global__ __launch_bounds__(256, 4) void k_edge3(
    const float* __restrict__ es, const float* __restrict__ evec,
    const float* __restrict__ enorm, const int* __restrict__ eidx,
    const int* __restrict__ perm,
    const float* __restrict__ Wf, const float* __restrict__ bf,
    const unsigned short* __restrict__ soh, const unsigned short* __restrict__ nvh,
    float* __restrict__ out_s, float* __restrict__ out_v) {
    const int t = threadIdx.x & 127;
    const int grp = blockIdx.x * 2 + (threadIdx.x >> 7);
    const int beg = grp * RUN;
    const int end = (beg + RUN < NE) ? beg + RUN : NE;
    if (beg >= end) return;

    float wf[ESZ][3];
#pragma unroll
    for (int k = 0; k < ESZ; ++k)
        for (int c = 0; c < 3; ++c)
            wf[k][c] = Wf[k * 384 + c * ND + t];
    float bfr[3];
    for (int c = 0; c < 3; ++c) bfr[c] = bf[c * ND + t];

    int eA = __builtin_amdgcn_readfirstlane(perm[beg]);
    int srcA = __builtin_amdgcn_readfirstlane(eidx[2 * eA]);
    int dstA = __builtin_amdgcn_readfirstlane(eidx[2 * eA + 1]);
    float nrmA = enorm[eA];
    float evA0 = evec[3 * eA + 0], evA1 = evec[3 * eA + 1], evA2 = evec[3 * eA + 2];
    float erA[ESZ];
#pragma unroll
    for (int k = 0; k < ESZ; ++k) erA[k] = es[(long)eA * ESZ + k];
    unsigned short gA0, gA1, gA2, hA0, hA1, hA2;
    {
        const unsigned short* sp = soh + (long)srcA * 384;
        gA0 = sp[t]; gA1 = sp[ND + t]; gA2 = sp[2 * ND + t];
        const unsigned short* np = nvh + (long)srcA * 384;
        hA0 = np[t]; hA1 = np[ND + t]; hA2 = np[2 * ND + t];
    }

    int cur_dst = -1;
    float as = 0.0f, av0 = 0.0f, av1 = 0.0f, av2 = 0.0f;

#pragma unroll 2
    for (int i = beg; i < end; ++i) {
        int ip = (i + 1 < end) ? i + 1 : end - 1;
        int eB = __builtin_amdgcn_readfirstlane(perm[ip]);
        int srcB = __builtin_amdgcn_readfirstlane(eidx[2 * eB]);
        int dstB = __builtin_amdgcn_readfirstlane(eidx[2 * eB + 1]);
        float nrmB = enorm[eB];
        float evB0 = evec[3 * eB + 0], evB1 = evec[3 * eB + 1], evB2 = evec[3 * eB + 2];
        float erB[ESZ];
#pragma unroll
        for (int k = 0; k < ESZ; ++k) erB[k] = es[(long)eB * ESZ + k];
        unsigned short gB0, gB1, gB2, hB0, hB1, hB2;
        {
            const unsigned short* sp = soh + (long)srcB * 384;
            gB0 = sp[t]; gB1 = sp[ND + t]; gB2 = sp[2 * ND + t];
            const unsigned short* np = nvh + (long)srcB * 384;
            hB0 = np[t]; hB1 = np[ND + t]; hB2 = np[2 * ND + t];
        }

        if (dstA != cur_dst) {
            if (cur_dst >= 0) {
                atomicAdd(&out_s[(long)cur_dst * ND + t], as);
                atomicAdd(&out_v[(long)cur_dst * 384 + 0 * ND + t], av0);
                atomicAdd(&out_v[(long)cur_dst * 384 + 1 * ND + t], av1);
                atomicAdd(&out_v[(long)cur_dst * 384 + 2 * ND + t], av2);
            }
            cur_dst = dstA;
            as = 0.0f; av0 = 0.0f; av1 = 0.0f; av2 = 0.0f;
        }
        float f0 = bfr[0], f1 = bfr[1], f2 = bfr[2];
#pragma unroll
        for (int k = 0; k < ESZ; ++k) {
            f0 += erA[k] * wf[k][0];
            f1 += erA[k] * wf[k][1];
            f2 += erA[k] * wf[k][2];
        }
        float fcv = (nrmA < CUT) ? 0.5f * (__cosf(PI_F * nrmA * (1.0f / CUT)) + 1.0f)
                                 : 0.0f;
        f0 *= fcv * bf2f(gA0);
        f1 *= fcv * bf2f(gA1);
        f2 *= fcv * bf2f(gA2);
        as  += f2;
        av0 += bf2f(hA0) * f0 + f1 * evA0;
        av1 += bf2f(hA1) * f0 + f1 * evA1;
        av2 += bf2f(hA2) * f0 + f1 * evA2;

        srcA = srcB; dstA = dstB; nrmA = nrmB;
        evA0 = evB0; evA1 = evB1; evA2 = evB2;
#pragma unroll
        for (int k = 0; k < ESZ; ++k) erA[k] = erB[k];
        gA0 = gB0; gA1 = gB1; gA2 = gB2;
        hA0 = hB0; hA1 = hB1; hA2 = hB2;
    }
    atomicAdd(&out_s[(long)cur_dst * ND + t], as);
    atomicAdd(&out_v[(long)cur_dst * 384 + 0 * ND + t], av0);
    atomicAdd(&out_v[(long)cur_dst * 384 + 1 * ND + t], av1);
    atomicAdd(&out_v[(long)cur_dst * 384 + 2 * ND + t], av2);
}

// ---------------------------------------------------------------------------
// k_uv: Uv/Vv (bf16) = v @ WU / v @ WV over flat (60000 x 128) view of out_v
// ---------------------------------------------------------------------------
__global__ __launch_bounds__(256) void k_uv(
    const float* __restrict__ out_v,
    const unsigned short* __restrict__ WUp, const unsigned short* __restrict__ WVp,
    unsigned short* __restrict__ Uvh, unsigned short* __restrict__ Vvh) {
    const int lane = threadIdx.x & 63;
    const int wid = blockIdx.x * 4 + (threadIdx.x >> 6);
    const int m0 = wid * 16;
    if (m0 >= NN * 3) return;
    const int ml = lane & 15, q = lane >> 4;

    short8 a[4];
#pragma unroll
    for (int kb = 0; kb < 4; ++kb) {
        const float* p = out_v + (long)(m0 + ml) * 128 + kb * 32 + q * 8;
        float4 x = *(const float4*)p;
        float4 y = *(const float4*)(p + 4);
        short8 s;
        s[0] = (short)f2bf(x.x); s[1] = (short)f2bf(x.y);
        s[2] = (short)f2bf(x.z); s[3] = (short)f2bf(x.w);
        s[4] = (short)f2bf(y.x); s[5] = (short)f2bf(y.y);
        s[6] = (short)f2bf(y.z); s[7] = (short)f2bf(y.w);
        a[kb] = s;
    }

#pragma unroll
    for (int nt = 0; nt < 8; ++nt) {
        f32x4 u = {0.f, 0.f, 0.f, 0.f}, v = {0.f, 0.f, 0.f, 0.f};
#pragma unroll
        for (int kb = 0; kb < 4; ++kb) {
            short8 bu = *(const short8*)(WUp + ((nt * 4 + kb) * 64 + lane) * 8);
            short8 bv = *(const short8*)(WVp + ((nt * 4 + kb) * 64 + lane) * 8);
            u = __builtin_amdgcn_mfma_f32_16x16x32_bf16(a[kb], bu, u, 0, 0, 0);
            v = __builtin_amdgcn_mfma_f32_16x16x32_bf16(a[kb], bv, v, 0, 0, 0);
        }
#pragma unroll
        for (int r = 0; r < 4; ++r) {
            long o = (long)(m0 + q * 4 + r) * 128 + nt * 16 + ml;
            Uvh[o] = f2bf(u[r]);
            Vvh[o] = f2bf(v[r]);
        }
    }
}

// ---------------------------------------------------------------------------
// k_mid: Vv_sq, ip; cat = bf16([s | Vv_sq])
// ---------------------------------------------------------------------------
__global__ __launch_bounds__(256) void k_mid(
    const float* __restrict__ out_s,
    const unsigned short* __restrict__ Uvh, const unsigned short* __restrict__ Vvh,
    unsigned short* __restrict__ cat, float* __restrict__ ipb) {
    int i = blockIdx.x * 256 + threadIdx.x;   // 0 .. 2,560,000
    int n = i >> 7, c = i & 127;
    float vsq = 0.f, ipv = 0.f;
#pragma unroll
    for (int ax = 0; ax < 3; ++ax) {
        long o = (long)(n * 3 + ax) * 128 + c;
        float vv = bf2f(Vvh[o]);
        float uu = bf2f(Uvh[o]);
        vsq += vv * vv;
        ipv += uu * vv;
    }
    cat[(long)n * 256 + c] = f2bf(out_s[(long)n * 128 + c]);
    cat[(long)n * 256 + 128 + c] = f2bf(vsq);
    ipb[(long)n * 128 + c] = ipv;
}

// ---------------------------------------------------------------------------
// k_att: a = silu(cat@Wa1+ba1)@Wa2+ba2; s += a_ss + a_sv*ip; v += a_vv*Uv
// ---------------------------------------------------------------------------
__global__ __launch_bounds__(256) void k_att(
    const unsigned short* __restrict__ cat,
    const unsigned short* __restrict__ Wa1p, const float* __restrict__ ba1,
    const unsigned short* __restrict__ Wa2p, const float* __restrict__ ba2,
    const float* __restrict__ ipb, const unsigned short* __restrict__ Uvh,
    float* __restrict__ out_s, float* __restrict__ out_v) {
    const int lane = threadIdx.x & 63;
    const int wv = threadIdx.x >> 6;
    const int wid = blockIdx.x * 4 + wv;
    const int m0 = wid * 16;
    if (m0 >= NN) return;
    const int ml = lane & 15, q = lane >> 4;
    __shared__ unsigned short lsh[4][16][136];

    short8 a1[8];
#pragma unroll
    for (int kb = 0; kb < 8; ++kb)
        a1[kb] = *(const short8*)(cat + (long)(m0 + ml) * 256 + kb * 32 + q * 8);

#pragma unroll
    for (int nt = 0; nt < 8; ++nt) {
        float b = ba1[nt * 16 + ml];
        f32x4 acc = {b, b, b, b};
#pragma unroll
        for (int kb = 0; kb < 8; ++kb) {
            short8 bf = *(const short8*)(Wa1p + ((nt * 8 + kb) * 64 + lane) * 8);
            acc = __builtin_amdgcn_mfma_f32_16x16x32_bf16(a1[kb], bf, acc, 0, 0, 0);
        }
#pragma unroll
        for (int r = 0; r < 4; ++r)
            lsh[wv][q * 4 + r][nt * 16 + ml] = f2bf(silu_f(acc[r]));
    }

    short8 h[4];
#pragma unroll
    for (int kb = 0; kb < 4; ++kb)
        h[kb] = *(const short8*)(&lsh[wv][ml][kb * 32 + q * 8]);

    // a_ss (tiles 0..7) paired with a_sv (tiles 8..15): update s
#pragma unroll
    for (int nt = 0; nt < 8; ++nt) {
        float b0 = ba2[nt * 16 + ml];
        float b1 = ba2[128 + nt * 16 + ml];
        f32x4 aS = {b0, b0, b0, b0};
        f32x4 aG = {b1, b1, b1, b1};
#pragma unroll
        for (int kb = 0; kb < 4; ++kb) {
            short8 bS = *(const short8*)(Wa2p + (((nt) * 4 + kb) * 64 + lane) * 8);
            short8 bG = *(const short8*)(Wa2p + (((nt + 8) * 4 + kb) * 64 + lane) * 8);
            aS = __builtin_amdgcn_mfma_f32_16x16x32_bf16(h[kb], bS, aS, 0, 0, 0);
            aG = __builtin_amdgcn_mfma_f32_16x16x32_bf16(h[kb], bG, aG, 0, 0, 0);
        }
#pragma unroll
        for (int r = 0; r < 4; ++r) {
            long grow = m0 + q * 4 + r;
            long o = grow * 128 + nt * 16 + ml;
            float ipv = ipb[o];
            out_s[o] = out_s[o] + aS[r] + aG[r] * ipv;
        }
    }

    // a_vv (tiles 16..23): update v
#pragma unroll
    for (int nt = 0; nt < 8; ++nt) {
        float b2 = ba2[256 + nt * 16 + ml];
        f32x4 aV = {b2, b2, b2, b2};
#pragma unroll
        for (int kb = 0; kb < 4; ++kb) {
            short8 bV = *(const short8*)(Wa2p + (((nt + 16) * 4 + kb) * 64 + lane) * 8);
            aV = __builtin_amdgcn_mfma_f32_16x16x32_bf16(h[kb], bV, aV, 0, 0, 0);
        }
#pragma unroll
        for (int r = 0; r < 4; ++r) {
            long grow = m0 + q * 4 + r;
            int c = nt * 16 + ml;
#pragma unroll
            for (int ax = 0; ax < 3; ++ax) {
                float u = bf2f(Uvh[(grow * 3 + ax) * 128 + c]);
                long o = grow * 384 + ax * 128 + c;
                out_v[o] = out_v[o] + aV[r] * u;
            }
        }
    }
}

// ---------------------------------------------------------------------------
extern "C" void kernel_launch(void* const* d_in, const int* in_sizes, int n_in,
                              void* d_out, int out_size, void* d_ws, size_t ws_size,
                              hipStream_t stream) {
    const float* ns    = (const float*)d_in[0];
    const float* nsv   = (const float*)d_in[1];
    const float* es    = (const float*)d_in[2];
    const float* evec  = (const float*)d_in[3];
    const float* enorm = (const float*)d_in[4];
    const int*   eidx  = (const int*)d_in[5];
    const float* Wf    = (const float*)d_in[6];
    const float* bf    = (const float*)d_in[7];
    const float* Wm1   = (const float*)d_in[8];
    const float* bm1   = (const float*)d_in[9];
    const float* Wm2   = (const float*)d_in[10];
    const float* bm2   = (const float*)d_in[11];
    const float* WU    = (const float*)d_in[12];
    const float* WV    = (const float*)d_in[13];
    const float* Wa1   = (const float*)d_in[14];
    const float* ba1   = (const float*)d_in[15];
    const float* Wa2   = (const float*)d_in[16];
    const float* ba2   = (const float*)d_in[17];

    float* out_s = (float*)d_out;
    float* out_v = out_s + (size_t)NN * ND;

    // ---- workspace layout (time-aliased union after the persistent region) ----
    char* w = (char*)d_ws;
    unsigned short* p1  = (unsigned short*)(w + 0);        //  32,768 B
    unsigned short* p2  = (unsigned short*)(w + 32768);    //  98,304 B
    unsigned short* pU  = (unsigned short*)(w + 131072);   //  32,768 B
    unsigned short* pV  = (unsigned short*)(w + 163840);   //  32,768 B
    unsigned short* pa1 = (unsigned short*)(w + 196608);   //  65,536 B
    unsigned short* pa2 = (unsigned short*)(w + 262144);   //  98,304 B
    int* counts = (int*)(w + 360448);                      //  80,000 B
    int* offs   = (int*)(w + 440576);                      //  80,004 B
    int* cursor = (int*)(w + 520704);                      //  80,000 B
    int* perm   = (int*)(w + 600832);                      // 2,400,000 B
    char* u0 = w + 3000832;
    // pre-edge occupants:
    unsigned short* soh = (unsigned short*)(u0);               // 15,360,000 B
    unsigned short* nvh = (unsigned short*)(u0 + 15360000);    // 15,360,000 B
    unsigned short* nsb = (unsigned short*)(u0 + 30720000);    //  5,120,000 B
    // post-edge occupants (alias the above; soh/nvh/nsb dead after k_edge3):
    unsigned short* Uvh = (unsigned short*)(u0);               // 15,360,000 B
    unsigned short* Vvh = (unsigned short*)(u0 + 15360000);    // 15,360,000 B
    unsigned short* cat = (unsigned short*)(u0 + 30720000);    // 10,240,000 B
    float*          ipb = (float*)(u0 + 40960000);             // 10,240,000 B

    hipMemsetAsync(counts, 0, (size_t)NN * sizeof(int), stream);
    k_prep<<<7500, 256, 0, stream>>>((const float4*)ns, (const float4*)nsv,
                                     (float4*)out_s, (float4*)out_v,
                                     (ushort4*)nsb, (ushort4*)nvh);
    k_packw<<<704, 256, 0, stream>>>(Wm1, Wm2, WU, WV, Wa1, Wa2,
                                     p1, p2, pU, pV, pa1, pa2);
    k_hist<<<(NE + 255) / 256, 256, 0, stream>>>(eidx, counts);
    k_scan<<<1, SCAN_T, 0, stream>>>(counts, offs, cursor);
    k_scatter<<<(NE + 255) / 256, 256, 0, stream>>>(eidx, cursor, perm);
    k_mlp<<<313, 256, 0, stream>>>(nsb, p1, bm1, p2, bm2, soh);
    k_edge3<<<NGRP / 2, 256, 0, stream>>>(es, evec, enorm, eidx, perm,
                                          Wf, bf, soh, nvh, out_s, out_v);
    k_uv<<<938, 256, 0, stream>>>(out_v, pU, pV, Uvh, Vvh);
    k_mid<<<10000, 256, 0, stream>>>(out_s, Uvh, Vvh, cat, ipb);
    k_att<<<313, 256, 0, stream>>>(cat, pa1, ba1, pa2, ba2, ipb, Uvh,
                                   out_s, out_v);
}

// Round 7
// 588.596 us; speedup vs baseline: 2.3198x; 1.2234x over previous
//
#include <hip/hip_runtime.h>

#define ND 128          // NODE_SIZE
#define ESZ 20          // EDGE_SIZE
#define NN 20000        // N_NODES
#define NE 600000       // N_EDGES
#define PI_F 3.14159265358979323846f
#define CUT 5.0f

using short8 = __attribute__((ext_vector_type(8))) short;   // 8 bf16 (4 VGPR)
using f32x4  = __attribute__((ext_vector_type(4))) float;   // MFMA C/D
using hh2    = __attribute__((ext_vector_type(2))) _Float16;

__device__ __forceinline__ float silu_f(float x) { return x / (1.0f + __expf(-x)); }

__device__ __forceinline__ unsigned short f2bf(float x) {
    unsigned u = __float_as_uint(x);
    unsigned r = (u + 0x7FFFu + ((u >> 16) & 1u)) >> 16;
    return (unsigned short)r;
}
__device__ __forceinline__ float bf2f(unsigned short h) {
    return __uint_as_float(((unsigned)h) << 16);
}
__device__ __forceinline__ unsigned pack2h(float x, float y) {
    _Float16 a = (_Float16)x, b = (_Float16)y;
    unsigned short ua = __builtin_bit_cast(unsigned short, a);
    unsigned short ub = __builtin_bit_cast(unsigned short, b);
    return (unsigned)ua | ((unsigned)ub << 16);
}
__device__ __forceinline__ float dot2u(unsigned a, hh2 b, float acc) {
    return __builtin_amdgcn_fdot2(__builtin_bit_cast(hh2, a), b, acc, false);
}

// ---------------------------------------------------------------------------
// weight pack helper (bf16 B-fragment layout for 16x16x32 MFMA)
// ---------------------------------------------------------------------------
__device__ __forceinline__ void pack_w(const float* __restrict__ W,
                                       unsigned short* __restrict__ P,
                                       int s, int K, int N) {
    int k = s / N, n = s - k * N;
    int dst = ((((n >> 4) * (K >> 5) + (k >> 5)) * 64) +
               (((k >> 3) & 3) << 4) + (n & 15)) * 8 + (k & 7);
    P[dst] = f2bf(W[s]);
}

// ---------------------------------------------------------------------------
// k_front: fused prep (node copy/pack, weight packs, Wf fp16 pack,
// es*fc fp16 pack, dst histogram) — ranged over global thread id
// ---------------------------------------------------------------------------
#define R0 1920000L
#define R1 (R0 + 180224L)
#define R2 (R1 + 4608L)
#define R3 (R2 + 600000L)
#define R4 (R3 + 600000L)

__global__ __launch_bounds__(256) void k_front(
    const float4* __restrict__ ns4, const float4* __restrict__ nsv4,
    const float* __restrict__ es, const float* __restrict__ enorm,
    const int* __restrict__ eidx,
    const float* __restrict__ Wf, const float* __restrict__ bfb,
    const float* __restrict__ Wm1, const float* __restrict__ Wm2,
    const float* __restrict__ WU, const float* __restrict__ WV,
    const float* __restrict__ Wa1, const float* __restrict__ Wa2,
    float4* __restrict__ outs4, float4* __restrict__ outv4,
    ushort4* __restrict__ nsb4, ushort4* __restrict__ nvh4,
    unsigned short* __restrict__ p1, unsigned short* __restrict__ p2,
    unsigned short* __restrict__ pU, unsigned short* __restrict__ pV,
    unsigned short* __restrict__ pa1, unsigned short* __restrict__ pa2,
    unsigned* __restrict__ wfh, unsigned* __restrict__ eshu,
    int* __restrict__ counts) {
    long gid = (long)blockIdx.x * 256 + threadIdx.x;
    if (gid < R0) {
        long i = gid;
        const long S4 = (long)NN * ND / 4;
        if (i < S4) {
            float4 v = ns4[i];
            outs4[i] = v;
            ushort4 h; h.x = f2bf(v.x); h.y = f2bf(v.y); h.z = f2bf(v.z); h.w = f2bf(v.w);
            nsb4[i] = h;
        }
        float4 w = nsv4[i];
        outv4[i] = w;
        ushort4 h2; h2.x = f2bf(w.x); h2.y = f2bf(w.y); h2.z = f2bf(w.z); h2.w = f2bf(w.w);
        nvh4[i] = h2;
    } else if (gid < R1) {
        int i = (int)(gid - R0);
        if      (i <  16384) pack_w(Wm1, p1, i,          128, 128);
        else if (i <  65536) pack_w(Wm2, p2, i - 16384,  128, 384);
        else if (i <  81920) pack_w(WU,  pU, i - 65536,  128, 128);
        else if (i <  98304) pack_w(WV,  pV, i - 81920,  128, 128);
        else if (i < 131072) pack_w(Wa1, pa1, i - 98304, 256, 128);
        else                 pack_w(Wa2, pa2, i - 131072,128, 384);
    } else if (gid < R2) {
        int j = (int)(gid - R1);        // 12*384
        int p = j / 384, cc = j - p * 384;
        float a = 0.f, b = 0.f;
        if (p < 10) { a = Wf[(2 * p) * 384 + cc]; b = Wf[(2 * p + 1) * 384 + cc]; }
        else if (p == 10) { a = bfb[cc]; }
        wfh[p * 384 + cc] = pack2h(a, b);
    } else if (gid < R3) {
        int e = (int)(gid - R2);
        float nrm = enorm[e];
        float fc = (nrm < CUT) ? 0.5f * (__cosf(PI_F * nrm * (1.0f / CUT)) + 1.0f) : 0.0f;
        const float* er = es + (long)e * ESZ;
        unsigned* dst = eshu + (long)e * 12;
#pragma unroll
        for (int p = 0; p < 10; ++p)
            dst[p] = pack2h(er[2 * p] * fc, er[2 * p + 1] * fc);
        dst[10] = pack2h(fc, 0.f);
        dst[11] = 0u;
    } else if (gid < R4) {
        int e = (int)(gid - R3);
        atomicAdd(&counts[eidx[2 * e + 1]], 1);
    }
}

// ---------------------------------------------------------------------------
// k_mlp: soh(bf16) = silu(nsb @ Wm1 + bm1) @ Wm2 + bm2
// ---------------------------------------------------------------------------
__global__ __launch_bounds__(256) void k_mlp(
    const unsigned short* __restrict__ nsb,
    const unsigned short* __restrict__ Wm1p, const float* __restrict__ bm1,
    const unsigned short* __restrict__ Wm2p, const float* __restrict__ bm2,
    unsigned short* __restrict__ soh) {
    const int lane = threadIdx.x & 63;
    const int wv = threadIdx.x >> 6;
    const int wid = blockIdx.x * 4 + wv;
    const int m0 = wid * 16;
    if (m0 >= NN) return;
    const int ml = lane & 15, q = lane >> 4;
    __shared__ unsigned short lsh[4][16][136];

    short8 a1[4];
#pragma unroll
    for (int kb = 0; kb < 4; ++kb)
        a1[kb] = *(const short8*)(nsb + (long)(m0 + ml) * ND + kb * 32 + q * 8);

#pragma unroll
    for (int nt = 0; nt < 8; ++nt) {
        float b = bm1[nt * 16 + ml];
        f32x4 acc = {b, b, b, b};
#pragma unroll
        for (int kb = 0; kb < 4; ++kb) {
            short8 bf = *(const short8*)(Wm1p + ((nt * 4 + kb) * 64 + lane) * 8);
            acc = __builtin_amdgcn_mfma_f32_16x16x32_bf16(a1[kb], bf, acc, 0, 0, 0);
        }
#pragma unroll
        for (int r = 0; r < 4; ++r)
            lsh[wv][q * 4 + r][nt * 16 + ml] = f2bf(silu_f(acc[r]));
    }
    __syncthreads();

    short8 a2[4];
#pragma unroll
    for (int kb = 0; kb < 4; ++kb)
        a2[kb] = *(const short8*)(&lsh[wv][ml][kb * 32 + q * 8]);

#pragma unroll
    for (int nt = 0; nt < 24; ++nt) {
        float b = bm2[nt * 16 + ml];
        f32x4 acc = {b, b, b, b};
#pragma unroll
        for (int kb = 0; kb < 4; ++kb) {
            short8 bf = *(const short8*)(Wm2p + ((nt * 4 + kb) * 64 + lane) * 8);
            acc = __builtin_amdgcn_mfma_f32_16x16x32_bf16(a2[kb], bf, acc, 0, 0, 0);
        }
#pragma unroll
        for (int r = 0; r < 4; ++r)
            soh[(long)(m0 + q * 4 + r) * 384 + nt * 16 + ml] = f2bf(acc[r]);
    }
}

// ---------------------------------------------------------------------------
// CSR scan + scatter
// ---------------------------------------------------------------------------
#define SCAN_T 1024
__global__ __launch_bounds__(SCAN_T) void k_scan(const int* __restrict__ counts,
                                                 int* __restrict__ offsets,
                                                 int* __restrict__ cursor) {
    __shared__ int part[SCAN_T];
    const int t = threadIdx.x;
    const int CPT = (NN + SCAN_T - 1) / SCAN_T;
    const int base = t * CPT;
    int sum = 0;
    for (int i = 0; i < CPT; ++i) {
        int idx = base + i;
        if (idx < NN) sum += counts[idx];
    }
    part[t] = sum;
    __syncthreads();
    for (int off = 1; off < SCAN_T; off <<= 1) {
        int v = (t >= off) ? part[t - off] : 0;
        __syncthreads();
        part[t] += v;
        __syncthreads();
    }
    int run = (t == 0) ? 0 : part[t - 1];
    for (int i = 0; i < CPT; ++i) {
        int idx = base + i;
        if (idx < NN) {
            offsets[idx] = run;
            cursor[idx] = run;
            run += counts[idx];
        }
    }
    if (t == SCAN_T - 1) offsets[NN] = run;
}

__global__ __launch_bounds__(256) void k_scatter(const int* __restrict__ eidx,
                                                 int* __restrict__ cursor,
                                                 int* __restrict__ perm) {
    int e = blockIdx.x * 256 + threadIdx.x;
    if (e < NE) {
        int pos = atomicAdd(&cursor[eidx[2 * e + 1]], 1);
        perm[pos] = e;
    }
}

// ---------------------------------------------------------------------------
// k_edge4: segmented reduction over dst-sorted edges.
// fp16-dot2 filter (fc+bias folded into esh/wfh), unroll-2 role-swap
// pipeline (no register rotation), SGPR edge data, bf16 gathers.
// Stage suffix S goes at the END of identifiers (q0A) to avoid the
// preprocessor pasting digit+.x into one pp-number token.
// ---------------------------------------------------------------------------
#define NGRP 8192
#define RUN ((NE + NGRP - 1) / NGRP)   // 74 (all group sizes even: 74 or 8)

#define LOADE(S, i_) {                                                        \
    int e_ = __builtin_amdgcn_readfirstlane(perm[i_]);                        \
    src##S = __builtin_amdgcn_readfirstlane(eidx[2 * e_]);                    \
    dst##S = __builtin_amdgcn_readfirstlane(eidx[2 * e_ + 1]);                \
    ev0##S = evec[3 * e_ + 0];                                                \
    ev1##S = evec[3 * e_ + 1];                                                \
    ev2##S = evec[3 * e_ + 2];                                                \
    const uint4* ep_ = esh4 + (long)e_ * 3;                                   \
    q0##S = ep_[0]; q1##S = ep_[1]; q2##S = ep_[2];                           \
    long sb_ = (long)src##S * 384;                                            \
    g0##S = soh[sb_ + t]; g1##S = soh[sb_ + 128 + t];                         \
    g2##S = soh[sb_ + 256 + t];                                               \
    h0##S = nvh[sb_ + t]; h1##S = nvh[sb_ + 128 + t];                         \
    h2##S = nvh[sb_ + 256 + t];                                               \
}

#define FLUSH() {                                                             \
    atomicAdd(&out_s[(long)cur_dst * ND + t], as);                            \
    atomicAdd(&out_v[(long)cur_dst * 384 + 0 * ND + t], av0);                 \
    atomicAdd(&out_v[(long)cur_dst * 384 + 1 * ND + t], av1);                 \
    atomicAdd(&out_v[(long)cur_dst * 384 + 2 * ND + t], av2);                 \
}

#define COMPE(S) {                                                            \
    if (dst##S != cur_dst) {                                                  \
        if (cur_dst >= 0) FLUSH();                                            \
        cur_dst = dst##S;                                                     \
        as = 0.f; av0 = 0.f; av1 = 0.f; av2 = 0.f;                            \
    }                                                                         \
    unsigned ea_[12] = {q0##S.x, q0##S.y, q0##S.z, q0##S.w,                   \
                        q1##S.x, q1##S.y, q1##S.z, q1##S.w,                   \
                        q2##S.x, q2##S.y, q2##S.z, q2##S.w};                  \
    float f0 = 0.f, f1 = 0.f, f2 = 0.f;                                       \
    _Pragma("unroll")                                                         \
    for (int p = 0; p < 12; ++p) {                                            \
        f0 = dot2u(ea_[p], wf[p][0], f0);                                     \
        f1 = dot2u(ea_[p], wf[p][1], f1);                                     \
        f2 = dot2u(ea_[p], wf[p][2], f2);                                     \
    }                                                                         \
    f0 *= bf2f(g0##S);                                                        \
    f1 *= bf2f(g1##S);                                                        \
    f2 *= bf2f(g2##S);                                                        \
    as  += f2;                                                                \
    av0 += bf2f(h0##S) * f0 + f1 * ev0##S;                                    \
    av1 += bf2f(h1##S) * f0 + f1 * ev1##S;                                    \
    av2 += bf2f(h2##S) * f0 + f1 * ev2##S;                                    \
}

__global__ __launch_bounds__(256, 4) void k_edge4(
    const uint4* __restrict__ esh4, const float* __restrict__ evec,
    const int* __restrict__ eidx, const int* __restrict__ perm,
    const unsigned* __restrict__ wfh,
    const unsigned short* __restrict__ soh, const unsigned short* __restrict__ nvh,
    float* __restrict__ out_s, float* __restrict__ out_v) {
    const int t = threadIdx.x & 127;
    const int grp = blockIdx.x * 2 + (threadIdx.x >> 7);
    const int beg = grp * RUN;
    const int end = (beg + RUN < NE) ? beg + RUN : NE;
    if (beg >= end) return;

    hh2 wf[12][3];
#pragma unroll
    for (int p = 0; p < 12; ++p)
#pragma unroll
        for (int c = 0; c < 3; ++c)
            wf[p][c] = __builtin_bit_cast(hh2, wfh[p * 384 + c * 128 + t]);

    int srcA, dstA, srcB, dstB;
    float ev0A, ev1A, ev2A, ev0B, ev1B, ev2B;
    uint4 q0A, q1A, q2A, q0B, q1B, q2B;
    unsigned short g0A, g1A, g2A, h0A, h1A, h2A;
    unsigned short g0B, g1B, g2B, h0B, h1B, h2B;

    LOADE(A, beg);
    LOADE(B, beg + 1);

    int cur_dst = -1;
    float as = 0.f, av0 = 0.f, av1 = 0.f, av2 = 0.f;

    for (int i = beg; i < end; i += 2) {
        COMPE(A);
        int ia = (i + 2 < end) ? i + 2 : end - 1;
        LOADE(A, ia);
        COMPE(B);
        int ib = (i + 3 < end) ? i + 3 : end - 1;
        LOADE(B, ib);
    }
    FLUSH();
}

// ---------------------------------------------------------------------------
// k_uv: Uv/Vv (bf16) = v @ WU / v @ WV over flat (60000 x 128) view of out_v
// ---------------------------------------------------------------------------
__global__ __launch_bounds__(256) void k_uv(
    const float* __restrict__ out_v,
    const unsigned short* __restrict__ WUp, const unsigned short* __restrict__ WVp,
    unsigned short* __restrict__ Uvh, unsigned short* __restrict__ Vvh) {
    const int lane = threadIdx.x & 63;
    const int wid = blockIdx.x * 4 + (threadIdx.x >> 6);
    const int m0 = wid * 16;
    if (m0 >= NN * 3) return;
    const int ml = lane & 15, q = lane >> 4;

    short8 a[4];
#pragma unroll
    for (int kb = 0; kb < 4; ++kb) {
        const float* p = out_v + (long)(m0 + ml) * 128 + kb * 32 + q * 8;
        float4 x = *(const float4*)p;
        float4 y = *(const float4*)(p + 4);
        short8 s;
        s[0] = (short)f2bf(x.x); s[1] = (short)f2bf(x.y);
        s[2] = (short)f2bf(x.z); s[3] = (short)f2bf(x.w);
        s[4] = (short)f2bf(y.x); s[5] = (short)f2bf(y.y);
        s[6] = (short)f2bf(y.z); s[7] = (short)f2bf(y.w);
        a[kb] = s;
    }

#pragma unroll
    for (int nt = 0; nt < 8; ++nt) {
        f32x4 u = {0.f, 0.f, 0.f, 0.f}, v = {0.f, 0.f, 0.f, 0.f};
#pragma unroll
        for (int kb = 0; kb < 4; ++kb) {
            short8 bu = *(const short8*)(WUp + ((nt * 4 + kb) * 64 + lane) * 8);
            short8 bv = *(const short8*)(WVp + ((nt * 4 + kb) * 64 + lane) * 8);
            u = __builtin_amdgcn_mfma_f32_16x16x32_bf16(a[kb], bu, u, 0, 0, 0);
            v = __builtin_amdgcn_mfma_f32_16x16x32_bf16(a[kb], bv, v, 0, 0, 0);
        }
#pragma unroll
        for (int r = 0; r < 4; ++r) {
            long o = (long)(m0 + q * 4 + r) * 128 + nt * 16 + ml;
            Uvh[o] = f2bf(u[r]);
            Vvh[o] = f2bf(v[r]);
        }
    }
}

// ---------------------------------------------------------------------------
// k_mid: Vv_sq, ip; cat = bf16([s | Vv_sq])
// ---------------------------------------------------------------------------
__global__ __launch_bounds__(256) void k_mid(
    const float* __restrict__ out_s,
    const unsigned short* __restrict__ Uvh, const unsigned short* __restrict__ Vvh,
    unsigned short* __restrict__ cat, float* __restrict__ ipb) {
    int i = blockIdx.x * 256 + threadIdx.x;
    int n = i >> 7, c = i & 127;
    float vsq = 0.f, ipv = 0.f;
#pragma unroll
    for (int ax = 0; ax < 3; ++ax) {
        long o = (long)(n * 3 + ax) * 128 + c;
        float vv = bf2f(Vvh[o]);
        float uu = bf2f(Uvh[o]);
        vsq += vv * vv;
        ipv += uu * vv;
    }
    cat[(long)n * 256 + c] = f2bf(out_s[(long)n * 128 + c]);
    cat[(long)n * 256 + 128 + c] = f2bf(vsq);
    ipb[(long)n * 128 + c] = ipv;
}

// ---------------------------------------------------------------------------
// k_att: a = silu(cat@Wa1+ba1)@Wa2+ba2; s += a_ss + a_sv*ip; v += a_vv*Uv
// ---------------------------------------------------------------------------
__global__ __launch_bounds__(256) void k_att(
    const unsigned short* __restrict__ cat,
    const unsigned short* __restrict__ Wa1p, const float* __restrict__ ba1,
    const unsigned short* __restrict__ Wa2p, const float* __restrict__ ba2,
    const float* __restrict__ ipb, const unsigned short* __restrict__ Uvh,
    float* __restrict__ out_s, float* __restrict__ out_v) {
    const int lane = threadIdx.x & 63;
    const int wv = threadIdx.x >> 6;
    const int wid = blockIdx.x * 4 + wv;
    const int m0 = wid * 16;
    if (m0 >= NN) return;
    const int ml = lane & 15, q = lane >> 4;
    __shared__ unsigned short lsh[4][16][136];

    short8 a1[8];
#pragma unroll
    for (int kb = 0; kb < 8; ++kb)
        a1[kb] = *(const short8*)(cat + (long)(m0 + ml) * 256 + kb * 32 + q * 8);

#pragma unroll
    for (int nt = 0; nt < 8; ++nt) {
        float b = ba1[nt * 16 + ml];
        f32x4 acc = {b, b, b, b};
#pragma unroll
        for (int kb = 0; kb < 8; ++kb) {
            short8 bf = *(const short8*)(Wa1p + ((nt * 8 + kb) * 64 + lane) * 8);
            acc = __builtin_amdgcn_mfma_f32_16x16x32_bf16(a1[kb], bf, acc, 0, 0, 0);
        }
#pragma unroll
        for (int r = 0; r < 4; ++r)
            lsh[wv][q * 4 + r][nt * 16 + ml] = f2bf(silu_f(acc[r]));
    }
    __syncthreads();

    short8 h[4];
#pragma unroll
    for (int kb = 0; kb < 4; ++kb)
        h[kb] = *(const short8*)(&lsh[wv][ml][kb * 32 + q * 8]);

#pragma unroll
    for (int nt = 0; nt < 8; ++nt) {
        float b0 = ba2[nt * 16 + ml];
        float b1 = ba2[128 + nt * 16 + ml];
        f32x4 aS = {b0, b0, b0, b0};
        f32x4 aG = {b1, b1, b1, b1};
#pragma unroll
        for (int kb = 0; kb < 4; ++kb) {
            short8 bS = *(const short8*)(Wa2p + (((nt) * 4 + kb) * 64 + lane) * 8);
            short8 bG = *(const short8*)(Wa2p + (((nt + 8) * 4 + kb) * 64 + lane) * 8);
            aS = __builtin_amdgcn_mfma_f32_16x16x32_bf16(h[kb], bS, aS, 0, 0, 0);
            aG = __builtin_amdgcn_mfma_f32_16x16x32_bf16(h[kb], bG, aG, 0, 0, 0);
        }
#pragma unroll
        for (int r = 0; r < 4; ++r) {
            long grow = m0 + q * 4 + r;
            long o = grow * 128 + nt * 16 + ml;
            float ipv = ipb[o];
            out_s[o] = out_s[o] + aS[r] + aG[r] * ipv;
        }
    }

#pragma unroll
    for (int nt = 0; nt < 8; ++nt) {
        float b2 = ba2[256 + nt * 16 + ml];
        f32x4 aV = {b2, b2, b2, b2};
#pragma unroll
        for (int kb = 0; kb < 4; ++kb) {
            short8 bV = *(const short8*)(Wa2p + (((nt + 16) * 4 + kb) * 64 + lane) * 8);
            aV = __builtin_amdgcn_mfma_f32_16x16x32_bf16(h[kb], bV, aV, 0, 0, 0);
        }
#pragma unroll
        for (int r = 0; r < 4; ++r) {
            long grow = m0 + q * 4 + r;
            int c = nt * 16 + ml;
#pragma unroll
            for (int ax = 0; ax < 3; ++ax) {
                float u = bf2f(Uvh[(grow * 3 + ax) * 128 + c]);
                long o = grow * 384 + ax * 128 + c;
                out_v[o] = out_v[o] + aV[r] * u;
            }
        }
    }
}

// ---------------------------------------------------------------------------
extern "C" void kernel_launch(void* const* d_in, const int* in_sizes, int n_in,
                              void* d_out, int out_size, void* d_ws, size_t ws_size,
                              hipStream_t stream) {
    const float* ns    = (const float*)d_in[0];
    const float* nsv   = (const float*)d_in[1];
    const float* es    = (const float*)d_in[2];
    const float* evec  = (const float*)d_in[3];
    const float* enorm = (const float*)d_in[4];
    const int*   eidx  = (const int*)d_in[5];
    const float* Wf    = (const float*)d_in[6];
    const float* bfb   = (const float*)d_in[7];
    const float* Wm1   = (const float*)d_in[8];
    const float* bm1   = (const float*)d_in[9];
    const float* Wm2   = (const float*)d_in[10];
    const float* bm2   = (const float*)d_in[11];
    const float* WU    = (const float*)d_in[12];
    const float* WV    = (const float*)d_in[13];
    const float* Wa1   = (const float*)d_in[14];
    const float* ba1   = (const float*)d_in[15];
    const float* Wa2   = (const float*)d_in[16];
    const float* ba2   = (const float*)d_in[17];

    float* out_s = (float*)d_out;
    float* out_v = out_s + (size_t)NN * ND;

    // ---- workspace layout ----
    char* w = (char*)d_ws;
    unsigned short* p1  = (unsigned short*)(w + 0);        //  32,768 B
    unsigned short* p2  = (unsigned short*)(w + 32768);    //  98,304 B
    unsigned short* pU  = (unsigned short*)(w + 131072);   //  32,768 B
    unsigned short* pV  = (unsigned short*)(w + 163840);   //  32,768 B
    unsigned short* pa1 = (unsigned short*)(w + 196608);   //  65,536 B
    unsigned short* pa2 = (unsigned short*)(w + 262144);   //  98,304 B
    unsigned* wfh = (unsigned*)(w + 360448);               //  18,432 B
    int* counts = (int*)(w + 378880);                      //  80,000 B
    int* offs   = (int*)(w + 458880);                      //  80,004 B
    int* cursor = (int*)(w + 538944);                      //  80,000 B
    int* perm   = (int*)(w + 618944);                      // 2,400,000 B
    char* u0 = w + 3018944;
    // pre-edge occupants:
    unsigned short* soh = (unsigned short*)(u0);               // 15,360,000 B
    unsigned short* nvh = (unsigned short*)(u0 + 15360000);    // 15,360,000 B
    unsigned short* nsb = (unsigned short*)(u0 + 30720000);    //  5,120,000 B
    unsigned* eshu      = (unsigned*)(u0 + 35840000);          // 28,800,000 B
    // post-edge occupants (alias pre-edge; all pre-edge dead after k_edge4):
    unsigned short* Uvh = (unsigned short*)(u0);               // 15,360,000 B
    unsigned short* Vvh = (unsigned short*)(u0 + 15360000);    // 15,360,000 B
    unsigned short* cat = (unsigned short*)(u0 + 30720000);    // 10,240,000 B
    float*          ipb = (float*)(u0 + 40960000);             // 10,240,000 B

    hipMemsetAsync(counts, 0, (size_t)NN * sizeof(int), stream);
    k_front<<<(int)((R4 + 255) / 256), 256, 0, stream>>>(
        (const float4*)ns, (const float4*)nsv, es, enorm, eidx, Wf, bfb,
        Wm1, Wm2, WU, WV, Wa1, Wa2,
        (float4*)out_s, (float4*)out_v, (ushort4*)nsb, (ushort4*)nvh,
        p1, p2, pU, pV, pa1, pa2, wfh, eshu, counts);
    k_scan<<<1, SCAN_T, 0, stream>>>(counts, offs, cursor);
    k_scatter<<<(NE + 255) / 256, 256, 0, stream>>>(eidx, cursor, perm);
    k_mlp<<<313, 256, 0, stream>>>(nsb, p1, bm1, p2, bm2, soh);
    k_edge4<<<NGRP / 2, 256, 0, stream>>>((const uint4*)eshu, evec, eidx, perm,
                                          wfh, soh, nvh, out_s, out_v);
    k_uv<<<938, 256, 0, stream>>>(out_v, pU, pV, Uvh, Vvh);
    k_mid<<<10000, 256, 0, stream>>>(out_s, Uvh, Vvh, cat, ipb);
    k_att<<<313, 256, 0, stream>>>(cat, pa1, ba1, pa2, ba2, ipb, Uvh,
                                   out_s, out_v);
}

// Round 8
// 575.022 us; speedup vs baseline: 2.3745x; 1.0236x over previous
//
#include <hip/hip_runtime.h>

#define ND 128          // NODE_SIZE
#define ESZ 20          // EDGE_SIZE
#define NN 20000        // N_NODES
#define NE 600000       // N_EDGES
#define PI_F 3.14159265358979323846f
#define CUT 5.0f

using short8 = __attribute__((ext_vector_type(8))) short;   // 8 bf16 (4 VGPR)
using f32x4  = __attribute__((ext_vector_type(4))) float;   // MFMA C/D
using hh2    = __attribute__((ext_vector_type(2))) _Float16;

__device__ __forceinline__ float silu_f(float x) { return x / (1.0f + __expf(-x)); }

__device__ __forceinline__ unsigned short f2bf(float x) {
    unsigned u = __float_as_uint(x);
    unsigned r = (u + 0x7FFFu + ((u >> 16) & 1u)) >> 16;
    return (unsigned short)r;
}
__device__ __forceinline__ float bf2f(unsigned short h) {
    return __uint_as_float(((unsigned)h) << 16);
}
__device__ __forceinline__ unsigned pack2h(float x, float y) {
    _Float16 a = (_Float16)x, b = (_Float16)y;
    unsigned short ua = __builtin_bit_cast(unsigned short, a);
    unsigned short ub = __builtin_bit_cast(unsigned short, b);
    return (unsigned)ua | ((unsigned)ub << 16);
}
__device__ __forceinline__ float dot2u(unsigned a, hh2 b, float acc) {
    return __builtin_amdgcn_fdot2(__builtin_bit_cast(hh2, a), b, acc, false);
}

// ---------------------------------------------------------------------------
// weight pack helper (bf16 B-fragment layout for 16x16x32 MFMA)
// ---------------------------------------------------------------------------
__device__ __forceinline__ void pack_w(const float* __restrict__ W,
                                       unsigned short* __restrict__ P,
                                       int s, int K, int N) {
    int k = s / N, n = s - k * N;
    int dst = ((((n >> 4) * (K >> 5) + (k >> 5)) * 64) +
               (((k >> 3) & 3) << 4) + (n & 15)) * 8 + (k & 7);
    P[dst] = f2bf(W[s]);
}

// ---------------------------------------------------------------------------
// k_front: fused prep (node copy/pack + gnh high halves, weight packs,
// Wf fp16 pack (11 rows), es*fc fp16 pack, dst histogram)
// ---------------------------------------------------------------------------
#define R0 1920000L
#define R1 (R0 + 180224L)
#define R2 (R1 + 4224L)
#define R3 (R2 + 600000L)
#define R4 (R3 + 600000L)

__global__ __launch_bounds__(256) void k_front(
    const float4* __restrict__ ns4, const float4* __restrict__ nsv4,
    const float* __restrict__ es, const float* __restrict__ enorm,
    const int* __restrict__ eidx,
    const float* __restrict__ Wf, const float* __restrict__ bfb,
    const float* __restrict__ Wm1, const float* __restrict__ Wm2,
    const float* __restrict__ WU, const float* __restrict__ WV,
    const float* __restrict__ Wa1, const float* __restrict__ Wa2,
    float4* __restrict__ outs4, float4* __restrict__ outv4,
    ushort4* __restrict__ nsb4, unsigned* __restrict__ gnh,
    unsigned short* __restrict__ p1, unsigned short* __restrict__ p2,
    unsigned short* __restrict__ pU, unsigned short* __restrict__ pV,
    unsigned short* __restrict__ pa1, unsigned short* __restrict__ pa2,
    unsigned* __restrict__ wfh, unsigned* __restrict__ eshu,
    int* __restrict__ counts) {
    long gid = (long)blockIdx.x * 256 + threadIdx.x;
    if (gid < R0) {
        long i = gid;
        const long S4 = (long)NN * ND / 4;
        if (i < S4) {
            float4 v = ns4[i];
            outs4[i] = v;
            ushort4 h; h.x = f2bf(v.x); h.y = f2bf(v.y); h.z = f2bf(v.z); h.w = f2bf(v.w);
            nsb4[i] = h;
        }
        float4 w = nsv4[i];
        outv4[i] = w;
        // nvh -> high halves of gnh
        unsigned short* gs = (unsigned short*)gnh;
        long b = i * 4;
        gs[(b + 0) * 2 + 1] = f2bf(w.x);
        gs[(b + 1) * 2 + 1] = f2bf(w.y);
        gs[(b + 2) * 2 + 1] = f2bf(w.z);
        gs[(b + 3) * 2 + 1] = f2bf(w.w);
    } else if (gid < R1) {
        int i = (int)(gid - R0);
        if      (i <  16384) pack_w(Wm1, p1, i,          128, 128);
        else if (i <  65536) pack_w(Wm2, p2, i - 16384,  128, 384);
        else if (i <  81920) pack_w(WU,  pU, i - 65536,  128, 128);
        else if (i <  98304) pack_w(WV,  pV, i - 81920,  128, 128);
        else if (i < 131072) pack_w(Wa1, pa1, i - 98304, 256, 128);
        else                 pack_w(Wa2, pa2, i - 131072,128, 384);
    } else if (gid < R2) {
        int j = (int)(gid - R1);        // 11*384
        int p = j / 384, cc = j - p * 384;
        float a = 0.f, b = 0.f;
        if (p < 10) { a = Wf[(2 * p) * 384 + cc]; b = Wf[(2 * p + 1) * 384 + cc]; }
        else if (p == 10) { a = bfb[cc]; }
        wfh[p * 384 + cc] = pack2h(a, b);
    } else if (gid < R3) {
        int e = (int)(gid - R2);
        float nrm = enorm[e];
        float fc = (nrm < CUT) ? 0.5f * (__cosf(PI_F * nrm * (1.0f / CUT)) + 1.0f) : 0.0f;
        const float* er = es + (long)e * ESZ;
        unsigned* dst = eshu + (long)e * 12;
#pragma unroll
        for (int p = 0; p < 10; ++p)
            dst[p] = pack2h(er[2 * p] * fc, er[2 * p + 1] * fc);
        dst[10] = pack2h(fc, 0.f);
        dst[11] = 0u;
    } else if (gid < R4) {
        int e = (int)(gid - R3);
        atomicAdd(&counts[eidx[2 * e + 1]], 1);
    }
}

// ---------------------------------------------------------------------------
// CSR scan
// ---------------------------------------------------------------------------
#define SCAN_T 1024
__global__ __launch_bounds__(SCAN_T) void k_scan(const int* __restrict__ counts,
                                                 int* __restrict__ offsets,
                                                 int* __restrict__ cursor) {
    __shared__ int part[SCAN_T];
    const int t = threadIdx.x;
    const int CPT = (NN + SCAN_T - 1) / SCAN_T;
    const int base = t * CPT;
    int sum = 0;
    for (int i = 0; i < CPT; ++i) {
        int idx = base + i;
        if (idx < NN) sum += counts[idx];
    }
    part[t] = sum;
    __syncthreads();
    for (int off = 1; off < SCAN_T; off <<= 1) {
        int v = (t >= off) ? part[t - off] : 0;
        __syncthreads();
        part[t] += v;
        __syncthreads();
    }
    int run = (t == 0) ? 0 : part[t - 1];
    for (int i = 0; i < CPT; ++i) {
        int idx = base + i;
        if (idx < NN) {
            offsets[idx] = run;
            cursor[idx] = run;
            run += counts[idx];
        }
    }
    if (t == SCAN_T - 1) offsets[NN] = run;
}

// ---------------------------------------------------------------------------
// k_sm: fused scatter (blocks [0, 2344)) + node MLP (blocks [2344, 2657)).
// MLP: gnh low halves = bf16( silu(nsb@Wm1+bm1) @ Wm2 + bm2 )
// ---------------------------------------------------------------------------
#define SCAT_B 2344
__global__ __launch_bounds__(256) void k_sm(
    const int* __restrict__ eidx, int* __restrict__ cursor, int* __restrict__ perm,
    const unsigned short* __restrict__ nsb,
    const unsigned short* __restrict__ Wm1p, const float* __restrict__ bm1,
    const unsigned short* __restrict__ Wm2p, const float* __restrict__ bm2,
    unsigned* __restrict__ gnh) {
    __shared__ unsigned short lsh[4][16][136];
    if (blockIdx.x < SCAT_B) {
        int e = blockIdx.x * 256 + threadIdx.x;
        if (e < NE) {
            int pos = atomicAdd(&cursor[eidx[2 * e + 1]], 1);
            perm[pos] = e;
        }
        return;
    }
    const int lane = threadIdx.x & 63;
    const int wv = threadIdx.x >> 6;
    const int wid = (blockIdx.x - SCAT_B) * 4 + wv;
    const int m0 = wid * 16;
    if (m0 >= NN) return;
    const int ml = lane & 15, q = lane >> 4;

    short8 a1[4];
#pragma unroll
    for (int kb = 0; kb < 4; ++kb)
        a1[kb] = *(const short8*)(nsb + (long)(m0 + ml) * ND + kb * 32 + q * 8);

#pragma unroll
    for (int nt = 0; nt < 8; ++nt) {
        float b = bm1[nt * 16 + ml];
        f32x4 acc = {b, b, b, b};
#pragma unroll
        for (int kb = 0; kb < 4; ++kb) {
            short8 bf = *(const short8*)(Wm1p + ((nt * 4 + kb) * 64 + lane) * 8);
            acc = __builtin_amdgcn_mfma_f32_16x16x32_bf16(a1[kb], bf, acc, 0, 0, 0);
        }
#pragma unroll
        for (int r = 0; r < 4; ++r)
            lsh[wv][q * 4 + r][nt * 16 + ml] = f2bf(silu_f(acc[r]));
    }
    __syncthreads();

    short8 a2[4];
#pragma unroll
    for (int kb = 0; kb < 4; ++kb)
        a2[kb] = *(const short8*)(&lsh[wv][ml][kb * 32 + q * 8]);

    unsigned short* gs = (unsigned short*)gnh;
#pragma unroll
    for (int nt = 0; nt < 24; ++nt) {
        float b = bm2[nt * 16 + ml];
        f32x4 acc = {b, b, b, b};
#pragma unroll
        for (int kb = 0; kb < 4; ++kb) {
            short8 bf = *(const short8*)(Wm2p + ((nt * 4 + kb) * 64 + lane) * 8);
            acc = __builtin_amdgcn_mfma_f32_16x16x32_bf16(a2[kb], bf, acc, 0, 0, 0);
        }
#pragma unroll
        for (int r = 0; r < 4; ++r) {
            long idx = (long)(m0 + q * 4 + r) * 384 + nt * 16 + ml;
            gs[idx * 2] = f2bf(acc[r]);   // low half of gnh
        }
    }
}

// ---------------------------------------------------------------------------
// k_edge5: segmented reduction over dst-sorted edges.
// fp16-dot2 filter (fc+bias folded; 11 pairs), unroll-2 role-swap pipeline,
// SGPR edge data, interleaved uint gathers from gnh (low=gate, high=nvec).
// ---------------------------------------------------------------------------
#define NGRP 8192
#define RUN ((NE + NGRP - 1) / NGRP)   // 74 (all group sizes even: 74 or 8)

#define LOADE(S, i_) {                                                        \
    int e_ = __builtin_amdgcn_readfirstlane(perm[i_]);                        \
    src##S = __builtin_amdgcn_readfirstlane(eidx[2 * e_]);                    \
    dst##S = __builtin_amdgcn_readfirstlane(eidx[2 * e_ + 1]);                \
    ev0##S = evec[3 * e_ + 0];                                                \
    ev1##S = evec[3 * e_ + 1];                                                \
    ev2##S = evec[3 * e_ + 2];                                                \
    const uint4* ep_ = esh4 + (long)e_ * 3;                                   \
    q0##S = ep_[0]; q1##S = ep_[1]; q2##S = ep_[2];                           \
    const unsigned* gp_ = gnh + (long)src##S * 384;                           \
    x0##S = gp_[t]; x1##S = gp_[128 + t]; x2##S = gp_[256 + t];               \
}

#define FLUSH() {                                                             \
    atomicAdd(&out_s[(long)cur_dst * ND + t], as);                            \
    atomicAdd(&out_v[(long)cur_dst * 384 + 0 * ND + t], av0);                 \
    atomicAdd(&out_v[(long)cur_dst * 384 + 1 * ND + t], av1);                 \
    atomicAdd(&out_v[(long)cur_dst * 384 + 2 * ND + t], av2);                 \
}

#define COMPE(S) {                                                            \
    if (dst##S != cur_dst) {                                                  \
        if (cur_dst >= 0) FLUSH();                                            \
        cur_dst = dst##S;                                                     \
        as = 0.f; av0 = 0.f; av1 = 0.f; av2 = 0.f;                            \
    }                                                                         \
    unsigned ea_[11] = {q0##S.x, q0##S.y, q0##S.z, q0##S.w,                   \
                        q1##S.x, q1##S.y, q1##S.z, q1##S.w,                   \
                        q2##S.x, q2##S.y, q2##S.z};                           \
    float f0 = 0.f, f1 = 0.f, f2 = 0.f;                                       \
    _Pragma("unroll")                                                         \
    for (int p = 0; p < 11; ++p) {                                            \
        f0 = dot2u(ea_[p], wf[p][0], f0);                                     \
        f1 = dot2u(ea_[p], wf[p][1], f1);                                     \
        f2 = dot2u(ea_[p], wf[p][2], f2);                                     \
    }                                                                         \
    f0 *= __uint_as_float(x0##S << 16);                                       \
    f1 *= __uint_as_float(x1##S << 16);                                       \
    f2 *= __uint_as_float(x2##S << 16);                                       \
    as  += f2;                                                                \
    av0 += __uint_as_float(x0##S & 0xffff0000u) * f0 + f1 * ev0##S;           \
    av1 += __uint_as_float(x1##S & 0xffff0000u) * f0 + f1 * ev1##S;           \
    av2 += __uint_as_float(x2##S & 0xffff0000u) * f0 + f1 * ev2##S;           \
}

__global__ __launch_bounds__(256, 4) void k_edge5(
    const uint4* __restrict__ esh4, const float* __restrict__ evec,
    const int* __restrict__ eidx, const int* __restrict__ perm,
    const unsigned* __restrict__ wfh, const unsigned* __restrict__ gnh,
    float* __restrict__ out_s, float* __restrict__ out_v) {
    const int t = threadIdx.x & 127;
    const int grp = blockIdx.x * 2 + (threadIdx.x >> 7);
    const int beg = grp * RUN;
    const int end = (beg + RUN < NE) ? beg + RUN : NE;
    if (beg >= end) return;

    hh2 wf[11][3];
#pragma unroll
    for (int p = 0; p < 11; ++p)
#pragma unroll
        for (int c = 0; c < 3; ++c)
            wf[p][c] = __builtin_bit_cast(hh2, wfh[p * 384 + c * 128 + t]);

    int srcA, dstA, srcB, dstB;
    float ev0A, ev1A, ev2A, ev0B, ev1B, ev2B;
    uint4 q0A, q1A, q2A, q0B, q1B, q2B;
    unsigned x0A, x1A, x2A, x0B, x1B, x2B;

    LOADE(A, beg);
    LOADE(B, beg + 1);

    int cur_dst = -1;
    float as = 0.f, av0 = 0.f, av1 = 0.f, av2 = 0.f;

    for (int i = beg; i < end; i += 2) {
        COMPE(A);
        int ia = (i + 2 < end) ? i + 2 : end - 1;
        LOADE(A, ia);
        COMPE(B);
        int ib = (i + 3 < end) ? i + 3 : end - 1;
        LOADE(B, ib);
    }
    FLUSH();
}

// ---------------------------------------------------------------------------
// k_uvm: per-axis GEMMs (Uv/Vv = v@WU / v@WV), fused vsq/ip:
// writes Uvh (bf16), cat = bf16([s | Vv_sq]), ipb (f32). One wave = 16 nodes.
// ---------------------------------------------------------------------------
__global__ __launch_bounds__(256) void k_uvm(
    const float* __restrict__ out_v, const float* __restrict__ out_s,
    const unsigned short* __restrict__ WUp, const unsigned short* __restrict__ WVp,
    unsigned short* __restrict__ Uvh, unsigned short* __restrict__ cat,
    float* __restrict__ ipb) {
    const int lane = threadIdx.x & 63;
    const int wid = blockIdx.x * 4 + (threadIdx.x >> 6);
    const int m0 = wid * 16;
    if (m0 >= NN) return;
    const int ml = lane & 15, q = lane >> 4;

    // s-half of cat (16 nodes x 128 ch = 2048 elems / 64 lanes)
#pragma unroll
    for (int j = 0; j < 32; ++j) {
        int idx = j * 64 + lane;
        int n = m0 + (idx >> 7), c = idx & 127;
        cat[(long)n * 256 + c] = f2bf(out_s[(long)n * 128 + c]);
    }

    short8 av[3][4];
#pragma unroll
    for (int ax = 0; ax < 3; ++ax)
#pragma unroll
        for (int kb = 0; kb < 4; ++kb) {
            const float* p = out_v + (long)(m0 + ml) * 384 + ax * 128 + kb * 32 + q * 8;
            float4 x = *(const float4*)p;
            float4 y = *(const float4*)(p + 4);
            short8 s;
            s[0] = (short)f2bf(x.x); s[1] = (short)f2bf(x.y);
            s[2] = (short)f2bf(x.z); s[3] = (short)f2bf(x.w);
            s[4] = (short)f2bf(y.x); s[5] = (short)f2bf(y.y);
            s[6] = (short)f2bf(y.z); s[7] = (short)f2bf(y.w);
            av[ax][kb] = s;
        }

#pragma unroll
    for (int nt = 0; nt < 8; ++nt) {
        f32x4 u0 = {0.f,0.f,0.f,0.f}, u1 = u0, u2 = u0;
        f32x4 v0 = u0, v1 = u0, v2 = u0;
#pragma unroll
        for (int kb = 0; kb < 4; ++kb) {
            short8 bu = *(const short8*)(WUp + ((nt * 4 + kb) * 64 + lane) * 8);
            short8 bv = *(const short8*)(WVp + ((nt * 4 + kb) * 64 + lane) * 8);
            u0 = __builtin_amdgcn_mfma_f32_16x16x32_bf16(av[0][kb], bu, u0, 0, 0, 0);
            u1 = __builtin_amdgcn_mfma_f32_16x16x32_bf16(av[1][kb], bu, u1, 0, 0, 0);
            u2 = __builtin_amdgcn_mfma_f32_16x16x32_bf16(av[2][kb], bu, u2, 0, 0, 0);
            v0 = __builtin_amdgcn_mfma_f32_16x16x32_bf16(av[0][kb], bv, v0, 0, 0, 0);
            v1 = __builtin_amdgcn_mfma_f32_16x16x32_bf16(av[1][kb], bv, v1, 0, 0, 0);
            v2 = __builtin_amdgcn_mfma_f32_16x16x32_bf16(av[2][kb], bv, v2, 0, 0, 0);
        }
        const int c = nt * 16 + ml;
#pragma unroll
        for (int r = 0; r < 4; ++r) {
            long grow = m0 + q * 4 + r;
            float vs  = v0[r] * v0[r] + v1[r] * v1[r] + v2[r] * v2[r];
            float ipv = u0[r] * v0[r] + u1[r] * v1[r] + u2[r] * v2[r];
            cat[grow * 256 + 128 + c] = f2bf(vs);
            ipb[grow * 128 + c] = ipv;
            Uvh[(grow * 3 + 0) * 128 + c] = f2bf(u0[r]);
            Uvh[(grow * 3 + 1) * 128 + c] = f2bf(u1[r]);
            Uvh[(grow * 3 + 2) * 128 + c] = f2bf(u2[r]);
        }
    }
}

// ---------------------------------------------------------------------------
// k_att: a = silu(cat@Wa1+ba1)@Wa2+ba2; s += a_ss + a_sv*ip; v += a_vv*Uv
// ---------------------------------------------------------------------------
__global__ __launch_bounds__(256) void k_att(
    const unsigned short* __restrict__ cat,
    const unsigned short* __restrict__ Wa1p, const float* __restrict__ ba1,
    const unsigned short* __restrict__ Wa2p, const float* __restrict__ ba2,
    const float* __restrict__ ipb, const unsigned short* __restrict__ Uvh,
    float* __restrict__ out_s, float* __restrict__ out_v) {
    const int lane = threadIdx.x & 63;
    const int wv = threadIdx.x >> 6;
    const int wid = blockIdx.x * 4 + wv;
    const int m0 = wid * 16;
    if (m0 >= NN) return;
    const int ml = lane & 15, q = lane >> 4;
    __shared__ unsigned short lsh[4][16][136];

    short8 a1[8];
#pragma unroll
    for (int kb = 0; kb < 8; ++kb)
        a1[kb] = *(const short8*)(cat + (long)(m0 + ml) * 256 + kb * 32 + q * 8);

#pragma unroll
    for (int nt = 0; nt < 8; ++nt) {
        float b = ba1[nt * 16 + ml];
        f32x4 acc = {b, b, b, b};
#pragma unroll
        for (int kb = 0; kb < 8; ++kb) {
            short8 bf = *(const short8*)(Wa1p + ((nt * 8 + kb) * 64 + lane) * 8);
            acc = __builtin_amdgcn_mfma_f32_16x16x32_bf16(a1[kb], bf, acc, 0, 0, 0);
        }
#pragma unroll
        for (int r = 0; r < 4; ++r)
            lsh[wv][q * 4 + r][nt * 16 + ml] = f2bf(silu_f(acc[r]));
    }
    __syncthreads();

    short8 h[4];
#pragma unroll
    for (int kb = 0; kb < 4; ++kb)
        h[kb] = *(const short8*)(&lsh[wv][ml][kb * 32 + q * 8]);

#pragma unroll
    for (int nt = 0; nt < 8; ++nt) {
        float b0 = ba2[nt * 16 + ml];
        float b1 = ba2[128 + nt * 16 + ml];
        f32x4 aS = {b0, b0, b0, b0};
        f32x4 aG = {b1, b1, b1, b1};
#pragma unroll
        for (int kb = 0; kb < 4; ++kb) {
            short8 bS = *(const short8*)(Wa2p + (((nt) * 4 + kb) * 64 + lane) * 8);
            short8 bG = *(const short8*)(Wa2p + (((nt + 8) * 4 + kb) * 64 + lane) * 8);
            aS = __builtin_amdgcn_mfma_f32_16x16x32_bf16(h[kb], bS, aS, 0, 0, 0);
            aG = __builtin_amdgcn_mfma_f32_16x16x32_bf16(h[kb], bG, aG, 0, 0, 0);
        }
#pragma unroll
        for (int r = 0; r < 4; ++r) {
            long grow = m0 + q * 4 + r;
            long o = grow * 128 + nt * 16 + ml;
            float ipv = ipb[o];
            out_s[o] = out_s[o] + aS[r] + aG[r] * ipv;
        }
    }

#pragma unroll
    for (int nt = 0; nt < 8; ++nt) {
        float b2 = ba2[256 + nt * 16 + ml];
        f32x4 aV = {b2, b2, b2, b2};
#pragma unroll
        for (int kb = 0; kb < 4; ++kb) {
            short8 bV = *(const short8*)(Wa2p + (((nt + 16) * 4 + kb) * 64 + lane) * 8);
            aV = __builtin_amdgcn_mfma_f32_16x16x32_bf16(h[kb], bV, aV, 0, 0, 0);
        }
#pragma unroll
        for (int r = 0; r < 4; ++r) {
            long grow = m0 + q * 4 + r;
            int c = nt * 16 + ml;
#pragma unroll
            for (int ax = 0; ax < 3; ++ax) {
                float u = bf2f(Uvh[(grow * 3 + ax) * 128 + c]);
                long o = grow * 384 + ax * 128 + c;
                out_v[o] = out_v[o] + aV[r] * u;
            }
        }
    }
}

// ---------------------------------------------------------------------------
extern "C" void kernel_launch(void* const* d_in, const int* in_sizes, int n_in,
                              void* d_out, int out_size, void* d_ws, size_t ws_size,
                              hipStream_t stream) {
    const float* ns    = (const float*)d_in[0];
    const float* nsv   = (const float*)d_in[1];
    const float* es    = (const float*)d_in[2];
    const float* evec  = (const float*)d_in[3];
    const float* enorm = (const float*)d_in[4];
    const int*   eidx  = (const int*)d_in[5];
    const float* Wf    = (const float*)d_in[6];
    const float* bfb   = (const float*)d_in[7];
    const float* Wm1   = (const float*)d_in[8];
    const float* bm1   = (const float*)d_in[9];
    const float* Wm2   = (const float*)d_in[10];
    const float* bm2   = (const float*)d_in[11];
    const float* WU    = (const float*)d_in[12];
    const float* WV    = (const float*)d_in[13];
    const float* Wa1   = (const float*)d_in[14];
    const float* ba1   = (const float*)d_in[15];
    const float* Wa2   = (const float*)d_in[16];
    const float* ba2   = (const float*)d_in[17];

    float* out_s = (float*)d_out;
    float* out_v = out_s + (size_t)NN * ND;

    // ---- workspace layout ----
    char* w = (char*)d_ws;
    unsigned short* p1  = (unsigned short*)(w + 0);        //  32,768 B
    unsigned short* p2  = (unsigned short*)(w + 32768);    //  98,304 B
    unsigned short* pU  = (unsigned short*)(w + 131072);   //  32,768 B
    unsigned short* pV  = (unsigned short*)(w + 163840);   //  32,768 B
    unsigned short* pa1 = (unsigned short*)(w + 196608);   //  65,536 B
    unsigned short* pa2 = (unsigned short*)(w + 262144);   //  98,304 B
    unsigned* wfh = (unsigned*)(w + 360448);               //  16,896 B
    int* counts = (int*)(w + 377344);                      //  80,000 B
    int* offs   = (int*)(w + 457344);                      //  80,004 B
    int* cursor = (int*)(w + 537408);                      //  80,000 B
    int* perm   = (int*)(w + 617408);                      // 2,400,000 B
    char* u0 = w + 3017408;
    // pre-edge occupants:
    unsigned* gnh       = (unsigned*)(u0);                     // 30,720,000 B
    unsigned short* nsb = (unsigned short*)(u0 + 30720000);    //  5,120,000 B
    unsigned* eshu      = (unsigned*)(u0 + 35840000);          // 28,800,000 B
    // post-edge occupants (alias gnh/nsb; dead after k_edge5):
    unsigned short* Uvh = (unsigned short*)(u0);               // 15,360,000 B
    unsigned short* cat = (unsigned short*)(u0 + 15360000);    // 10,240,000 B
    float*          ipb = (float*)(u0 + 25600000);             // 10,240,000 B

    hipMemsetAsync(counts, 0, (size_t)NN * sizeof(int), stream);
    k_front<<<(int)((R4 + 255) / 256), 256, 0, stream>>>(
        (const float4*)ns, (const float4*)nsv, es, enorm, eidx, Wf, bfb,
        Wm1, Wm2, WU, WV, Wa1, Wa2,
        (float4*)out_s, (float4*)out_v, (ushort4*)nsb, gnh,
        p1, p2, pU, pV, pa1, pa2, wfh, eshu, counts);
    k_scan<<<1, SCAN_T, 0, stream>>>(counts, offs, cursor);
    k_sm<<<SCAT_B + 313, 256, 0, stream>>>(eidx, cursor, perm,
                                           nsb, p1, bm1, p2, bm2, gnh);
    k_edge5<<<NGRP / 2, 256, 0, stream>>>((const uint4*)eshu, evec, eidx, perm,
                                          wfh, gnh, out_s, out_v);
    k_uvm<<<313, 256, 0, stream>>>(out_v, out_s, pU, pV, Uvh, cat, ipb);
    k_att<<<313, 256, 0, stream>>>(cat, pa1, ba1, pa2, ba2, ipb, Uvh,
                                   out_s, out_v);
}